// Round 1
// baseline (1734.872 us; speedup 1.0000x reference)
//
#include <hip/hip_runtime.h>

#define NCFG 8
#define NN 100000
#define NE 400000
#define NG 10
#define FEAT 97

// ---------------- CSR build ----------------
__global__ void k_hist(const int* __restrict__ src, int* __restrict__ deg, int e_count){
  int e = blockIdx.x*blockDim.x + threadIdx.x;
  if(e < e_count) atomicAdd(&deg[src[e]], 1);
}

// single block, 1024 threads; deg_cur holds deg on entry, exclusive prefix (cursor) on exit
__global__ __launch_bounds__(1024) void k_scan(int* __restrict__ deg_cur, int* __restrict__ rowptr,
                                               float* __restrict__ inv_deg, int n){
  __shared__ int wsum[16];
  __shared__ int carry_s;
  int tid = threadIdx.x, lane = tid & 63, w = tid >> 6;
  if(tid == 0) carry_s = 0;
  for(int base = 0; base < n; base += 4096){
    int i0 = base + tid*4;
    int v0 = (i0+0 < n) ? deg_cur[i0+0] : 0;
    int v1 = (i0+1 < n) ? deg_cur[i0+1] : 0;
    int v2 = (i0+2 < n) ? deg_cur[i0+2] : 0;
    int v3 = (i0+3 < n) ? deg_cur[i0+3] : 0;
    int s = v0+v1+v2+v3;
    int x = s;
    #pragma unroll
    for(int off=1; off<64; off<<=1){
      int t = __shfl_up(x, off, 64);
      if(lane >= off) x += t;
    }
    __syncthreads();                 // protect wsum/carry_s from prev iteration's readers
    if(lane == 63) wsum[w] = x;
    __syncthreads();
    if(w == 0){
      int y = (lane < 16) ? wsum[lane] : 0;
      #pragma unroll
      for(int off=1; off<16; off<<=1){
        int t = __shfl_up(y, off, 64);
        if(lane >= off) y += t;
      }
      if(lane < 16) wsum[lane] = y;
    }
    __syncthreads();
    int waveoff = (w > 0) ? wsum[w-1] : 0;
    int carry = carry_s;
    int run = carry + waveoff + (x - s);
    if(i0+0 < n){ rowptr[i0+0]=run; deg_cur[i0+0]=run; inv_deg[i0+0]=1.0f/(float)max(v0,1); run+=v0; }
    if(i0+1 < n){ rowptr[i0+1]=run; deg_cur[i0+1]=run; inv_deg[i0+1]=1.0f/(float)max(v1,1); run+=v1; }
    if(i0+2 < n){ rowptr[i0+2]=run; deg_cur[i0+2]=run; inv_deg[i0+2]=1.0f/(float)max(v2,1); run+=v2; }
    if(i0+3 < n){ rowptr[i0+3]=run; deg_cur[i0+3]=run; inv_deg[i0+3]=1.0f/(float)max(v3,1); run+=v3; }
    __syncthreads();
    if(tid == 0) carry_s = carry + wsum[15];
  }
  if(tid == 0) rowptr[n] = carry_s;
}

__global__ void k_fill(const int* __restrict__ src, const int* __restrict__ dst,
                       int* __restrict__ cursor, int* __restrict__ col, int e_count){
  int e = blockIdx.x*blockDim.x + threadIdx.x;
  if(e < e_count){
    int pos = atomicAdd(&cursor[src[e]], 1);
    col[pos] = dst[e];
  }
}

// embW1[o][j] = sum_k emb[o][k] * W1[k][j], k<32
__global__ void k_embW1(const float* __restrict__ emb, const float* __restrict__ W1,
                        float* __restrict__ embW1){
  int o = blockIdx.x, j = threadIdx.x;
  float s = 0.f;
  #pragma unroll
  for(int k=0;k<32;k++) s += emb[o*32+k] * W1[k*64+j];
  embW1[o*64+j] = s;
}

__global__ void k_offsets(const int* __restrict__ lengths, int* __restrict__ off){
  if(threadIdx.x == 0){
    int s = 0;
    for(int g=0; g<NG; g++){ off[g] = s; s += lengths[g]; }
    off[NG] = s;
  }
}

// ---------------- layer 1: y0 = feat[:,1:97] @ W1[32:,:] + embW1[op]  (per config) ----------------
__global__ __launch_bounds__(256) void k_layer1(const float* __restrict__ feat,
    const float* __restrict__ embW1, const float* __restrict__ W1,
    float* __restrict__ y0, int n_nodes){
  __shared__ float FT[96][68];      // transposed feature tile [k][node], pad 68 for banks
  __shared__ float W1s[96*64];
  __shared__ int ops[64];
  int tid = threadIdx.x;
  int nb = blockIdx.x * 64;
  for(int i=tid; i<96*64; i+=256) W1s[i] = W1[32*64 + i];
  size_t fbase = (size_t)nb * FEAT;
  for(int idx=tid; idx<64*FEAT; idx+=256){
    int r  = idx / FEAT;
    int cc = idx - r*FEAT;
    float v = (nb + r < n_nodes) ? feat[fbase + idx] : 0.f;
    if(cc == 0) ops[r] = (int)v;
    else        FT[cc-1][r] = v;
  }
  __syncthreads();
  int tn = (tid & 15) * 4;          // output cols
  int tm = (tid >> 4) * 4;          // nodes
  float acc[4][4] = {};
  #pragma unroll 4
  for(int f=0; f<96; f++){
    float4 a = *(const float4*)&FT[f][tm];
    float4 b = *(const float4*)&W1s[f*64 + tn];
    float av[4] = {a.x,a.y,a.z,a.w};
    float bv[4] = {b.x,b.y,b.z,b.w};
    #pragma unroll
    for(int i=0;i<4;i++)
      #pragma unroll
      for(int j=0;j<4;j++)
        acc[i][j] = fmaf(av[i], bv[j], acc[i][j]);
  }
  #pragma unroll
  for(int i=0;i<4;i++){
    int node = nb + tm + i;
    if(node < n_nodes){
      const float4 e = *(const float4*)&embW1[ops[tm+i]*64 + tn];
      float4 o;
      o.x = acc[i][0] + e.x; o.y = acc[i][1] + e.y;
      o.z = acc[i][2] + e.z; o.w = acc[i][3] + e.w;
      *(float4*)&y0[(size_t)node*64 + tn] = o;
    }
  }
}

// ---------------- layer 2: y1[n] = relu(inv*sum_nb y0[nb] + b1) @ W2 ----------------
__global__ __launch_bounds__(256) void k_layer2(const int* __restrict__ rowptr,
    const int* __restrict__ col, const float* __restrict__ inv_deg,
    const float* __restrict__ y0, const float* __restrict__ W2,
    const float* __restrict__ b1, float* __restrict__ y1, int n_nodes){
  __shared__ float w2s[64*64];
  int tid = threadIdx.x, lane = tid & 63;
  for(int i=tid; i<64*64; i+=256) w2s[i] = W2[i];
  __syncthreads();
  float w2r[64];                    // lane i holds column i of W2
  #pragma unroll
  for(int j=0;j<64;j++) w2r[j] = w2s[j*64 + lane];
  float b1v = b1[lane];
  int wid = blockIdx.x*4 + (tid >> 6);
  int stride = gridDim.x*4;
  for(int n = wid; n < n_nodes; n += stride){
    int kb = rowptr[n], ke = rowptr[n+1];
    float acc = 0.f;
    for(int k=kb; k<ke; k++){
      int d = col[k];
      acc += y0[(size_t)d*64 + lane];
    }
    float h = fmaxf(fmaf(acc, inv_deg[n], b1v), 0.f);
    float o0=0.f, o1=0.f, o2=0.f, o3=0.f;
    #pragma unroll
    for(int j=0;j<64;j+=4){
      float h0 = __uint_as_float(__builtin_amdgcn_readlane(__float_as_uint(h), j+0));
      float h1 = __uint_as_float(__builtin_amdgcn_readlane(__float_as_uint(h), j+1));
      float h2 = __uint_as_float(__builtin_amdgcn_readlane(__float_as_uint(h), j+2));
      float h3 = __uint_as_float(__builtin_amdgcn_readlane(__float_as_uint(h), j+3));
      o0 = fmaf(h0, w2r[j+0], o0);
      o1 = fmaf(h1, w2r[j+1], o1);
      o2 = fmaf(h2, w2r[j+2], o2);
      o3 = fmaf(h3, w2r[j+3], o3);
    }
    y1[(size_t)n*64 + lane] = (o0+o1)+(o2+o3);
  }
}

// ---------------- layer 3: r[n] = |relu(inv*sum_nb y1[nb] + b2) . Wp + bp| ----------------
__global__ __launch_bounds__(256) void k_layer3(const int* __restrict__ rowptr,
    const int* __restrict__ col, const float* __restrict__ inv_deg,
    const float* __restrict__ y1, const float* __restrict__ b2,
    const float* __restrict__ Wp, const float* __restrict__ bp,
    float* __restrict__ r_out, int n_nodes){
  int tid = threadIdx.x, lane = tid & 63;
  float b2v = b2[lane];
  float wpv = Wp[lane];
  float bpv = bp[0];
  int wid = blockIdx.x*4 + (tid >> 6);
  int stride = gridDim.x*4;
  for(int n = wid; n < n_nodes; n += stride){
    int kb = rowptr[n], ke = rowptr[n+1];
    float acc = 0.f;
    for(int k=kb; k<ke; k++){
      int d = col[k];
      acc += y1[(size_t)d*64 + lane];
    }
    float h = fmaxf(fmaf(acc, inv_deg[n], b2v), 0.f);
    float p = h * wpv;
    #pragma unroll
    for(int off=32; off>0; off>>=1) p += __shfl_xor(p, off, 64);
    if(lane == 0) r_out[n] = fabsf(p + bpv);
  }
}

// ---------------- pool: out[g*8+c] = sum over nodes of graph g of r_all[c][n] ----------------
__global__ __launch_bounds__(256) void k_pool(const float* __restrict__ r_all,
    const int* __restrict__ off, float* __restrict__ out){
  __shared__ float red[256];
  int b = blockIdx.x;               // b = g*8 + c
  int g = b >> 3, c = b & 7;
  int lo = off[g], hi = off[g+1];
  float s = 0.f;
  for(int i = lo + (int)threadIdx.x; i < hi; i += 256) s += r_all[(size_t)c*NN + i];
  red[threadIdx.x] = s;
  __syncthreads();
  for(int w=128; w>0; w>>=1){
    if((int)threadIdx.x < w) red[threadIdx.x] += red[threadIdx.x + w];
    __syncthreads();
  }
  if(threadIdx.x == 0) out[b] = red[0];
}

extern "C" void kernel_launch(void* const* d_in, const int* in_sizes, int n_in,
                              void* d_out, int out_size, void* d_ws, size_t ws_size,
                              hipStream_t stream){
  (void)in_sizes; (void)n_in; (void)out_size; (void)ws_size;
  const float* feat = (const float*)d_in[0];
  const int*   eidx = (const int*)d_in[1];
  const int*   lens = (const int*)d_in[2];
  const float* emb  = (const float*)d_in[3];
  const float* W1   = (const float*)d_in[4];
  const float* b1   = (const float*)d_in[5];
  const float* W2   = (const float*)d_in[6];
  const float* b2   = (const float*)d_in[7];
  const float* Wp   = (const float*)d_in[8];
  const float* bp   = (const float*)d_in[9];
  float* out = (float*)d_out;
  const int* src = eidx;
  const int* dst = eidx + NE;

  char* ws = (char*)d_ws;
  size_t o = 0;
  auto alloc = [&](size_t bytes)->char*{ char* p = ws + o; o = (o + bytes + 255) & ~(size_t)255; return p; };
  int*   rowptr = (int*)  alloc((NN+1)*4);
  int*   cursor = (int*)  alloc((size_t)NN*4);
  int*   colx   = (int*)  alloc((size_t)NE*4);
  float* invd   = (float*)alloc((size_t)NN*4);
  int*   goff   = (int*)  alloc((NG+1)*4);
  float* eW1    = (float*)alloc(128*64*4);
  float* y0     = (float*)alloc((size_t)NN*64*4);
  float* y1     = (float*)alloc((size_t)NN*64*4);
  float* r_all  = (float*)alloc((size_t)NCFG*NN*4);

  hipMemsetAsync(cursor, 0, (size_t)NN*4, stream);
  k_hist   <<<(NE+255)/256, 256, 0, stream>>>(src, cursor, NE);
  k_scan   <<<1, 1024, 0, stream>>>(cursor, rowptr, invd, NN);
  k_fill   <<<(NE+255)/256, 256, 0, stream>>>(src, dst, cursor, colx, NE);
  k_embW1  <<<128, 64, 0, stream>>>(emb, W1, eW1);
  k_offsets<<<1, 64, 0, stream>>>(lens, goff);

  for(int c=0; c<NCFG; c++){
    const float* fc = feat + (size_t)c*NN*FEAT;
    k_layer1<<<(NN+63)/64, 256, 0, stream>>>(fc, eW1, W1, y0, NN);
    k_layer2<<<2048, 256, 0, stream>>>(rowptr, colx, invd, y0, W2, b1, y1, NN);
    k_layer3<<<2048, 256, 0, stream>>>(rowptr, colx, invd, y1, b2, Wp, bp, r_all + (size_t)c*NN, NN);
  }
  k_pool<<<NCFG*NG, 256, 0, stream>>>(r_all, goff, out);
}

// Round 2
// 1257.227 us; speedup vs baseline: 1.3799x; 1.3799x over previous
//
#include <hip/hip_runtime.h>

#define NCFG 8
#define NN 100000
#define NE 400000
#define NG 10
#define FEAT 97

// ---------------- CSR build ----------------
__global__ void k_hist(const int* __restrict__ src, int* __restrict__ deg, int e_count){
  int e = blockIdx.x*blockDim.x + threadIdx.x;
  if(e < e_count) atomicAdd(&deg[src[e]], 1);
}

// single block, 1024 threads; deg_cur holds deg on entry, exclusive prefix (cursor) on exit
__global__ __launch_bounds__(1024) void k_scan(int* __restrict__ deg_cur, int* __restrict__ rowptr,
                                               float* __restrict__ inv_deg, int n){
  __shared__ int wsum[16];
  __shared__ int carry_s;
  int tid = threadIdx.x, lane = tid & 63, w = tid >> 6;
  if(tid == 0) carry_s = 0;
  for(int base = 0; base < n; base += 4096){
    int i0 = base + tid*4;
    int v0 = (i0+0 < n) ? deg_cur[i0+0] : 0;
    int v1 = (i0+1 < n) ? deg_cur[i0+1] : 0;
    int v2 = (i0+2 < n) ? deg_cur[i0+2] : 0;
    int v3 = (i0+3 < n) ? deg_cur[i0+3] : 0;
    int s = v0+v1+v2+v3;
    int x = s;
    #pragma unroll
    for(int off=1; off<64; off<<=1){
      int t = __shfl_up(x, off, 64);
      if(lane >= off) x += t;
    }
    __syncthreads();
    if(lane == 63) wsum[w] = x;
    __syncthreads();
    if(w == 0){
      int y = (lane < 16) ? wsum[lane] : 0;
      #pragma unroll
      for(int off=1; off<16; off<<=1){
        int t = __shfl_up(y, off, 64);
        if(lane >= off) y += t;
      }
      if(lane < 16) wsum[lane] = y;
    }
    __syncthreads();
    int waveoff = (w > 0) ? wsum[w-1] : 0;
    int carry = carry_s;
    int run = carry + waveoff + (x - s);
    if(i0+0 < n){ rowptr[i0+0]=run; deg_cur[i0+0]=run; inv_deg[i0+0]=1.0f/(float)max(v0,1); run+=v0; }
    if(i0+1 < n){ rowptr[i0+1]=run; deg_cur[i0+1]=run; inv_deg[i0+1]=1.0f/(float)max(v1,1); run+=v1; }
    if(i0+2 < n){ rowptr[i0+2]=run; deg_cur[i0+2]=run; inv_deg[i0+2]=1.0f/(float)max(v2,1); run+=v2; }
    if(i0+3 < n){ rowptr[i0+3]=run; deg_cur[i0+3]=run; inv_deg[i0+3]=1.0f/(float)max(v3,1); run+=v3; }
    __syncthreads();
    if(tid == 0) carry_s = carry + wsum[15];
  }
  if(tid == 0) rowptr[n] = carry_s;
}

__global__ void k_fill(const int* __restrict__ src, const int* __restrict__ dst,
                       int* __restrict__ cursor, int* __restrict__ col, int e_count){
  int e = blockIdx.x*blockDim.x + threadIdx.x;
  if(e < e_count){
    int pos = atomicAdd(&cursor[src[e]], 1);
    col[pos] = dst[e];
  }
}

// embW1[o][j] = sum_k emb[o][k] * W1[k][j], k<32
__global__ void k_embW1(const float* __restrict__ emb, const float* __restrict__ W1,
                        float* __restrict__ embW1){
  int o = blockIdx.x, j = threadIdx.x;
  float s = 0.f;
  #pragma unroll
  for(int k=0;k<32;k++) s += emb[o*32+k] * W1[k*64+j];
  embW1[o*64+j] = s;
}

__global__ void k_offsets(const int* __restrict__ lengths, int* __restrict__ off){
  if(threadIdx.x == 0){
    int s = 0;
    for(int g=0; g<NG; g++){ off[g] = s; s += lengths[g]; }
    off[NG] = s;
  }
}

// ---------------- gemm1: z = feat[:,1:97] @ W1[32:,:] + embW1[op]  (all configs) ----------------
__global__ __launch_bounds__(256) void k_gemm1(const float* __restrict__ feat,
    const float* __restrict__ embW1, const float* __restrict__ W1,
    float* __restrict__ z_all){
  __shared__ float FT[96][72];      // transposed feature tile [k][node]; pad 72: 16B-aligned cols, 4-way write conflicts only
  __shared__ float W1s[96*64];
  __shared__ int ops[64];
  int tid = threadIdx.x;
  int nb = blockIdx.x * 64;
  int cfg = blockIdx.y;
  const float* f = feat + (size_t)cfg*NN*FEAT;
  float* z = z_all + (size_t)cfg*NN*64;
  for(int i=tid; i<96*64; i+=256) W1s[i] = W1[32*64 + i];
  size_t fbase = (size_t)nb * FEAT;
  for(int idx=tid; idx<64*FEAT; idx+=256){
    int r  = idx / FEAT;
    int cc = idx - r*FEAT;
    float v = (nb + r < NN) ? f[fbase + idx] : 0.f;
    if(cc == 0) ops[r] = (int)v;
    else        FT[cc-1][r] = v;
  }
  __syncthreads();
  int tn = (tid & 15) * 4;          // output cols
  int tm = (tid >> 4) * 4;          // nodes
  float acc[4][4] = {};
  #pragma unroll 4
  for(int k=0; k<96; k++){
    float4 a = *(const float4*)&FT[k][tm];
    float4 b = *(const float4*)&W1s[k*64 + tn];
    float av[4] = {a.x,a.y,a.z,a.w};
    float bv[4] = {b.x,b.y,b.z,b.w};
    #pragma unroll
    for(int i=0;i<4;i++)
      #pragma unroll
      for(int j=0;j<4;j++)
        acc[i][j] = fmaf(av[i], bv[j], acc[i][j]);
  }
  #pragma unroll
  for(int i=0;i<4;i++){
    int node = nb + tm + i;
    if(node < NN){
      const float4 e = *(const float4*)&embW1[ops[tm+i]*64 + tn];
      float4 o;
      o.x = acc[i][0] + e.x; o.y = acc[i][1] + e.y;
      o.z = acc[i][2] + e.z; o.w = acc[i][3] + e.w;
      *(float4*)&z[(size_t)node*64 + tn] = o;
    }
  }
}

// ---------------- gemm2: z = h @ W2  (all configs) ----------------
__global__ __launch_bounds__(256) void k_gemm2(const float* __restrict__ h_all,
    const float* __restrict__ W2, float* __restrict__ z_all){
  __shared__ float HT[64][72];
  __shared__ float W2s[64*64];
  int tid = threadIdx.x;
  int nb = blockIdx.x * 64;
  int cfg = blockIdx.y;
  const float* h = h_all + (size_t)cfg*NN*64;
  float* z = z_all + (size_t)cfg*NN*64;
  for(int i=tid; i<64*64; i+=256) W2s[i] = W2[i];
  for(int idx=tid; idx<64*64; idx+=256){
    int r = idx >> 6, k = idx & 63;
    float v = (nb + r < NN) ? h[(size_t)(nb+r)*64 + k] : 0.f;
    HT[k][r] = v;
  }
  __syncthreads();
  int tn = (tid & 15) * 4;
  int tm = (tid >> 4) * 4;
  float acc[4][4] = {};
  #pragma unroll 4
  for(int k=0; k<64; k++){
    float4 a = *(const float4*)&HT[k][tm];
    float4 b = *(const float4*)&W2s[k*64 + tn];
    float av[4] = {a.x,a.y,a.z,a.w};
    float bv[4] = {b.x,b.y,b.z,b.w};
    #pragma unroll
    for(int i=0;i<4;i++)
      #pragma unroll
      for(int j=0;j<4;j++)
        acc[i][j] = fmaf(av[i], bv[j], acc[i][j]);
  }
  #pragma unroll
  for(int i=0;i<4;i++){
    int node = nb + tm + i;
    if(node < NN){
      float4 o; o.x=acc[i][0]; o.y=acc[i][1]; o.z=acc[i][2]; o.w=acc[i][3];
      *(float4*)&z[(size_t)node*64 + tn] = o;
    }
  }
}

// ---------------- gather1: h[n] = relu(inv*sum_nb z[nb] + b1)  (all configs) ----------------
// one wave per node; 4 lane-groups x float4 -> 4-deep load ILP, 1KB/wave per round
__global__ __launch_bounds__(256) void k_gather1(const int* __restrict__ rowptr,
    const int* __restrict__ col, const float* __restrict__ inv_deg,
    const float* __restrict__ z_all, const float* __restrict__ b1,
    float* __restrict__ h_all){
  int tid = threadIdx.x, lane = tid & 63;
  int n = (blockIdx.x << 2) + (tid >> 6);
  if(n >= NN) return;
  int cfg = blockIdx.y;
  const float* x = z_all + (size_t)cfg*NN*64;
  float* h = h_all + (size_t)cfg*NN*64;
  int l15 = lane & 15, g = lane >> 4;
  int kb = rowptr[n], ke = rowptr[n+1];
  float4 acc = {0.f,0.f,0.f,0.f};
  for(int base = kb; base < ke; base += 64){
    int kk = base + lane;
    int d = (kk < ke) ? col[kk] : 0;
    int cnt = min(64, ke - base);
    for(int k = g; k < cnt; k += 4){
      int dk = __shfl(d, k, 64);
      const float4 v = *(const float4*)(x + ((size_t)dk << 6) + (l15 << 2));
      acc.x += v.x; acc.y += v.y; acc.z += v.z; acc.w += v.w;
    }
  }
  #pragma unroll
  for(int off=16; off<=32; off<<=1){
    acc.x += __shfl_xor(acc.x, off, 64);
    acc.y += __shfl_xor(acc.y, off, 64);
    acc.z += __shfl_xor(acc.z, off, 64);
    acc.w += __shfl_xor(acc.w, off, 64);
  }
  float inv = inv_deg[n];
  const float4 b = *(const float4*)(b1 + (l15 << 2));
  float4 o;
  o.x = fmaxf(fmaf(acc.x, inv, b.x), 0.f);
  o.y = fmaxf(fmaf(acc.y, inv, b.y), 0.f);
  o.z = fmaxf(fmaf(acc.z, inv, b.z), 0.f);
  o.w = fmaxf(fmaf(acc.w, inv, b.w), 0.f);
  if(lane < 16) *(float4*)(h + ((size_t)n << 6) + (l15 << 2)) = o;
}

// ---------------- gather2: r[n] = |relu(inv*sum_nb z[nb] + b2) . Wp + bp| ----------------
__global__ __launch_bounds__(256) void k_gather2(const int* __restrict__ rowptr,
    const int* __restrict__ col, const float* __restrict__ inv_deg,
    const float* __restrict__ z_all, const float* __restrict__ b2,
    const float* __restrict__ Wp, const float* __restrict__ bp,
    float* __restrict__ r_all){
  int tid = threadIdx.x, lane = tid & 63;
  int n = (blockIdx.x << 2) + (tid >> 6);
  if(n >= NN) return;
  int cfg = blockIdx.y;
  const float* x = z_all + (size_t)cfg*NN*64;
  float* r_out = r_all + (size_t)cfg*NN;
  int l15 = lane & 15, g = lane >> 4;
  int kb = rowptr[n], ke = rowptr[n+1];
  float4 acc = {0.f,0.f,0.f,0.f};
  for(int base = kb; base < ke; base += 64){
    int kk = base + lane;
    int d = (kk < ke) ? col[kk] : 0;
    int cnt = min(64, ke - base);
    for(int k = g; k < cnt; k += 4){
      int dk = __shfl(d, k, 64);
      const float4 v = *(const float4*)(x + ((size_t)dk << 6) + (l15 << 2));
      acc.x += v.x; acc.y += v.y; acc.z += v.z; acc.w += v.w;
    }
  }
  #pragma unroll
  for(int off=16; off<=32; off<<=1){
    acc.x += __shfl_xor(acc.x, off, 64);
    acc.y += __shfl_xor(acc.y, off, 64);
    acc.z += __shfl_xor(acc.z, off, 64);
    acc.w += __shfl_xor(acc.w, off, 64);
  }
  float inv = inv_deg[n];
  const float4 b = *(const float4*)(b2 + (l15 << 2));
  const float4 wp = *(const float4*)(Wp + (l15 << 2));
  float p = fmaxf(fmaf(acc.x, inv, b.x), 0.f) * wp.x
          + fmaxf(fmaf(acc.y, inv, b.y), 0.f) * wp.y
          + fmaxf(fmaf(acc.z, inv, b.z), 0.f) * wp.z
          + fmaxf(fmaf(acc.w, inv, b.w), 0.f) * wp.w;
  #pragma unroll
  for(int off=1; off<16; off<<=1) p += __shfl_xor(p, off, 64);
  if(lane == 0) r_out[n] = fabsf(p + bp[0]);
}

// ---------------- pool: out[g*8+c] = sum over nodes of graph g of r_all[c][n] ----------------
__global__ __launch_bounds__(256) void k_pool(const float* __restrict__ r_all,
    const int* __restrict__ off, float* __restrict__ out){
  __shared__ float red[256];
  int b = blockIdx.x;               // b = g*8 + c
  int g = b >> 3, c = b & 7;
  int lo = off[g], hi = off[g+1];
  float s = 0.f;
  for(int i = lo + (int)threadIdx.x; i < hi; i += 256) s += r_all[(size_t)c*NN + i];
  red[threadIdx.x] = s;
  __syncthreads();
  for(int w=128; w>0; w>>=1){
    if((int)threadIdx.x < w) red[threadIdx.x] += red[threadIdx.x + w];
    __syncthreads();
  }
  if(threadIdx.x == 0) out[b] = red[0];
}

extern "C" void kernel_launch(void* const* d_in, const int* in_sizes, int n_in,
                              void* d_out, int out_size, void* d_ws, size_t ws_size,
                              hipStream_t stream){
  (void)in_sizes; (void)n_in; (void)out_size; (void)ws_size;
  const float* feat = (const float*)d_in[0];
  const int*   eidx = (const int*)d_in[1];
  const int*   lens = (const int*)d_in[2];
  const float* emb  = (const float*)d_in[3];
  const float* W1   = (const float*)d_in[4];
  const float* b1   = (const float*)d_in[5];
  const float* W2   = (const float*)d_in[6];
  const float* b2   = (const float*)d_in[7];
  const float* Wp   = (const float*)d_in[8];
  const float* bp   = (const float*)d_in[9];
  float* out = (float*)d_out;
  const int* src = eidx;
  const int* dst = eidx + NE;

  char* ws = (char*)d_ws;
  size_t o = 0;
  auto alloc = [&](size_t bytes)->char*{ char* p = ws + o; o = (o + bytes + 255) & ~(size_t)255; return p; };
  int*   rowptr = (int*)  alloc((NN+1)*4);
  int*   cursor = (int*)  alloc((size_t)NN*4);
  int*   colx   = (int*)  alloc((size_t)NE*4);
  float* invd   = (float*)alloc((size_t)NN*4);
  int*   goff   = (int*)  alloc((NG+1)*4);
  float* eW1    = (float*)alloc(128*64*4);
  float* r_all  = (float*)alloc((size_t)NCFG*NN*4);
  float* z_all  = (float*)alloc((size_t)NCFG*NN*64*4);   // 204.8 MB
  float* h_all  = (float*)alloc((size_t)NCFG*NN*64*4);   // 204.8 MB

  hipMemsetAsync(cursor, 0, (size_t)NN*4, stream);
  k_hist   <<<(NE+255)/256, 256, 0, stream>>>(src, cursor, NE);
  k_scan   <<<1, 1024, 0, stream>>>(cursor, rowptr, invd, NN);
  k_fill   <<<(NE+255)/256, 256, 0, stream>>>(src, dst, cursor, colx, NE);
  k_embW1  <<<128, 64, 0, stream>>>(emb, W1, eW1);
  k_offsets<<<1, 64, 0, stream>>>(lens, goff);

  dim3 ggemm((NN+63)/64, NCFG);
  dim3 ggath((NN+3)/4, NCFG);
  k_gemm1  <<<ggemm, 256, 0, stream>>>(feat, eW1, W1, z_all);
  k_gather1<<<ggath, 256, 0, stream>>>(rowptr, colx, invd, z_all, b1, h_all);
  k_gemm2  <<<ggemm, 256, 0, stream>>>(h_all, W2, z_all);
  k_gather2<<<ggath, 256, 0, stream>>>(rowptr, colx, invd, z_all, b2, Wp, bp, r_all);
  k_pool   <<<NCFG*NG, 256, 0, stream>>>(r_all, goff, out);
}

// Round 3
// 984.998 us; speedup vs baseline: 1.7613x; 1.2764x over previous
//
#include <hip/hip_runtime.h>

#define NCFG 8
#define NN 100000
#define NE 400000
#define NG 10
#define FEAT 97

typedef __attribute__((ext_vector_type(8))) short bf16x8;
typedef __attribute__((ext_vector_type(4))) float f32x4;

__device__ inline short f2bf(float x){
  unsigned u = __float_as_uint(x);
  unsigned r = u + 0x7FFFu + ((u >> 16) & 1u);
  return (short)(r >> 16);
}
__device__ inline float bf2f(short h){
  return __uint_as_float(((unsigned)(unsigned short)h) << 16);
}

// ---------------- CSR build ----------------
__global__ void k_hist(const int* __restrict__ src, int* __restrict__ deg, int e_count){
  int e = blockIdx.x*blockDim.x + threadIdx.x;
  if(e < e_count) atomicAdd(&deg[src[e]], 1);
}

__global__ __launch_bounds__(1024) void k_scan(int* __restrict__ deg_cur, int* __restrict__ rowptr,
                                               float* __restrict__ inv_deg, int n){
  __shared__ int wsum[16];
  __shared__ int carry_s;
  int tid = threadIdx.x, lane = tid & 63, w = tid >> 6;
  if(tid == 0) carry_s = 0;
  for(int base = 0; base < n; base += 4096){
    int i0 = base + tid*4;
    int v0 = (i0+0 < n) ? deg_cur[i0+0] : 0;
    int v1 = (i0+1 < n) ? deg_cur[i0+1] : 0;
    int v2 = (i0+2 < n) ? deg_cur[i0+2] : 0;
    int v3 = (i0+3 < n) ? deg_cur[i0+3] : 0;
    int s = v0+v1+v2+v3;
    int x = s;
    #pragma unroll
    for(int off=1; off<64; off<<=1){
      int t = __shfl_up(x, off, 64);
      if(lane >= off) x += t;
    }
    __syncthreads();
    if(lane == 63) wsum[w] = x;
    __syncthreads();
    if(w == 0){
      int y = (lane < 16) ? wsum[lane] : 0;
      #pragma unroll
      for(int off=1; off<16; off<<=1){
        int t = __shfl_up(y, off, 64);
        if(lane >= off) y += t;
      }
      if(lane < 16) wsum[lane] = y;
    }
    __syncthreads();
    int waveoff = (w > 0) ? wsum[w-1] : 0;
    int carry = carry_s;
    int run = carry + waveoff + (x - s);
    if(i0+0 < n){ rowptr[i0+0]=run; deg_cur[i0+0]=run; inv_deg[i0+0]=1.0f/(float)max(v0,1); run+=v0; }
    if(i0+1 < n){ rowptr[i0+1]=run; deg_cur[i0+1]=run; inv_deg[i0+1]=1.0f/(float)max(v1,1); run+=v1; }
    if(i0+2 < n){ rowptr[i0+2]=run; deg_cur[i0+2]=run; inv_deg[i0+2]=1.0f/(float)max(v2,1); run+=v2; }
    if(i0+3 < n){ rowptr[i0+3]=run; deg_cur[i0+3]=run; inv_deg[i0+3]=1.0f/(float)max(v3,1); run+=v3; }
    __syncthreads();
    if(tid == 0) carry_s = carry + wsum[15];
  }
  if(tid == 0) rowptr[n] = carry_s;
}

__global__ void k_fill(const int* __restrict__ src, const int* __restrict__ dst,
                       int* __restrict__ cursor, int* __restrict__ col, int e_count){
  int e = blockIdx.x*blockDim.x + threadIdx.x;
  if(e < e_count){
    int pos = atomicAdd(&cursor[src[e]], 1);
    col[pos] = dst[e];
  }
}

__global__ void k_embW1(const float* __restrict__ emb, const float* __restrict__ W1,
                        float* __restrict__ embW1){
  int o = blockIdx.x, j = threadIdx.x;
  float s = 0.f;
  #pragma unroll
  for(int k=0;k<32;k++) s += emb[o*32+k] * W1[k*64+j];
  embW1[o*64+j] = s;
}

__global__ void k_offsets(const int* __restrict__ lengths, int* __restrict__ off){
  if(threadIdx.x == 0){
    int s = 0;
    for(int g=0; g<NG; g++){ off[g] = s; s += lengths[g]; }
    off[NG] = s;
  }
}

// ---------------- gemm1 (MFMA): z = feat[:,1:97] @ W1[32:,:] + embW1[op] ----------------
// 64 rows x 64 cols per block, 4 waves, each wave 16 rows.
// bf16 split: z = Ahi@Bhi + Alo@Bhi + Ahi@Blo  (error ~2^-18 relative)
__global__ __launch_bounds__(256) void k_gemm1(const float* __restrict__ feat,
    const float* __restrict__ embW1, const float* __restrict__ W1,
    float* __restrict__ z_all){
  __shared__ short Bhi[3*4*64*8];   // 12 KB, fragment-order: [kc][t][lane][i]
  __shared__ short Blo[3*4*64*8];   // 12 KB
  __shared__ int ops[64];
  int tid = threadIdx.x;
  int nb = blockIdx.x * 64;
  int cfg = blockIdx.y;
  const float* f = feat + (size_t)cfg*NN*FEAT;
  float* z = z_all + (size_t)cfg*NN*64;

  // stage B fragments: elem(kc,t,l,i) = W1[32 + kc*32 + (l>>4)*8 + i][t*16 + (l&15)]
  for(int e = tid; e < 3*4*64*8; e += 256){
    int i = e & 7, l = (e >> 3) & 63, t = (e >> 9) & 3, kc = e >> 11;
    int k = kc*32 + ((l>>4)<<3) + i;
    int c = t*16 + (l & 15);
    float wv = W1[(32 + k)*64 + c];
    short h = f2bf(wv);
    Bhi[e] = h;
    Blo[e] = f2bf(wv - bf2f(h));
  }
  if(tid < 64){
    int node = nb + tid; if(node >= NN) node = NN-1;
    ops[tid] = (int)f[(size_t)node*FEAT];
  }
  __syncthreads();

  int w = tid >> 6, l = tid & 63;
  int row = nb + w*16 + (l & 15);
  if(row >= NN) row = NN-1;                       // clamp; stores guarded
  const float* frow = f + (size_t)row*FEAT + 1 + ((l>>4)<<3);

  f32x4 acc[4] = {{0,0,0,0},{0,0,0,0},{0,0,0,0},{0,0,0,0}};
  #pragma unroll
  for(int kc = 0; kc < 3; kc++){
    float a[8];
    #pragma unroll
    for(int i=0;i<8;i++) a[i] = frow[kc*32 + i];
    bf16x8 ahi, alo;
    #pragma unroll
    for(int i=0;i<8;i++){
      short h = f2bf(a[i]);
      ahi[i] = h;
      alo[i] = f2bf(a[i] - bf2f(h));
    }
    #pragma unroll
    for(int t=0;t<4;t++){
      const bf16x8 bh = *(const bf16x8*)&Bhi[((kc*4 + t)*64 + l)*8];
      const bf16x8 bl = *(const bf16x8*)&Blo[((kc*4 + t)*64 + l)*8];
      acc[t] = __builtin_amdgcn_mfma_f32_16x16x32_bf16(ahi, bh, acc[t], 0,0,0);
      acc[t] = __builtin_amdgcn_mfma_f32_16x16x32_bf16(alo, bh, acc[t], 0,0,0);
      acc[t] = __builtin_amdgcn_mfma_f32_16x16x32_bf16(ahi, bl, acc[t], 0,0,0);
    }
  }
  // C/D: row_in_tile = (l>>4)*4 + j, col = t*16 + (l&15)   [m89-verified]
  int r0 = w*16 + ((l>>4)<<2);
  int cb = l & 15;
  #pragma unroll
  for(int j=0;j<4;j++){
    int node = nb + r0 + j;
    if(node < NN){
      int op = ops[r0 + j];
      #pragma unroll
      for(int t=0;t<4;t++){
        int c = t*16 + cb;
        z[(size_t)node*64 + c] = acc[t][j] + embW1[op*64 + c];
      }
    }
  }
}

// ---------------- gemm2 (MFMA): z = h @ W2 ----------------
__global__ __launch_bounds__(256) void k_gemm2(const float* __restrict__ h_all,
    const float* __restrict__ W2, float* __restrict__ z_all){
  __shared__ short Bhi[2*4*64*8];   // 8 KB
  __shared__ short Blo[2*4*64*8];   // 8 KB
  int tid = threadIdx.x;
  int nb = blockIdx.x * 64;
  int cfg = blockIdx.y;
  const float* hsrc = h_all + (size_t)cfg*NN*64;
  float* z = z_all + (size_t)cfg*NN*64;

  for(int e = tid; e < 2*4*64*8; e += 256){
    int i = e & 7, l = (e >> 3) & 63, t = (e >> 9) & 3, kc = e >> 11;
    int k = kc*32 + ((l>>4)<<3) + i;
    int c = t*16 + (l & 15);
    float wv = W2[k*64 + c];
    short h = f2bf(wv);
    Bhi[e] = h;
    Blo[e] = f2bf(wv - bf2f(h));
  }
  __syncthreads();

  int w = tid >> 6, l = tid & 63;
  int row = nb + w*16 + (l & 15);
  if(row >= NN) row = NN-1;
  const float* hrow = hsrc + (size_t)row*64 + ((l>>4)<<3);

  f32x4 acc[4] = {{0,0,0,0},{0,0,0,0},{0,0,0,0},{0,0,0,0}};
  #pragma unroll
  for(int kc = 0; kc < 2; kc++){
    float4 a0 = *(const float4*)(hrow + kc*32);
    float4 a1 = *(const float4*)(hrow + kc*32 + 4);
    float a[8] = {a0.x,a0.y,a0.z,a0.w,a1.x,a1.y,a1.z,a1.w};
    bf16x8 ahi, alo;
    #pragma unroll
    for(int i=0;i<8;i++){
      short h = f2bf(a[i]);
      ahi[i] = h;
      alo[i] = f2bf(a[i] - bf2f(h));
    }
    #pragma unroll
    for(int t=0;t<4;t++){
      const bf16x8 bh = *(const bf16x8*)&Bhi[((kc*4 + t)*64 + l)*8];
      const bf16x8 bl = *(const bf16x8*)&Blo[((kc*4 + t)*64 + l)*8];
      acc[t] = __builtin_amdgcn_mfma_f32_16x16x32_bf16(ahi, bh, acc[t], 0,0,0);
      acc[t] = __builtin_amdgcn_mfma_f32_16x16x32_bf16(alo, bh, acc[t], 0,0,0);
      acc[t] = __builtin_amdgcn_mfma_f32_16x16x32_bf16(ahi, bl, acc[t], 0,0,0);
    }
  }
  int r0 = w*16 + ((l>>4)<<2);
  int cb = l & 15;
  #pragma unroll
  for(int j=0;j<4;j++){
    int node = nb + r0 + j;
    if(node < NN){
      #pragma unroll
      for(int t=0;t<4;t++){
        z[(size_t)node*64 + t*16 + cb] = acc[t][j];
      }
    }
  }
}

// ---------------- gather1: h[n] = relu(inv*sum_nb z[nb] + b1) ----------------
__global__ __launch_bounds__(256) void k_gather1(const int* __restrict__ rowptr,
    const int* __restrict__ col, const float* __restrict__ inv_deg,
    const float* __restrict__ z_all, const float* __restrict__ b1,
    float* __restrict__ h_all){
  int tid = threadIdx.x, lane = tid & 63;
  int n = (blockIdx.x << 2) + (tid >> 6);
  if(n >= NN) return;
  int cfg = blockIdx.y;
  const float* x = z_all + (size_t)cfg*NN*64;
  float* h = h_all + (size_t)cfg*NN*64;
  int l15 = lane & 15, g = lane >> 4;
  int kb = rowptr[n], ke = rowptr[n+1];
  float4 acc = {0.f,0.f,0.f,0.f};
  for(int base = kb; base < ke; base += 64){
    int kk = base + lane;
    int d = (kk < ke) ? col[kk] : 0;
    int cnt = min(64, ke - base);
    for(int k = g; k < cnt; k += 4){
      int dk = __shfl(d, k, 64);
      const float4 v = *(const float4*)(x + ((size_t)dk << 6) + (l15 << 2));
      acc.x += v.x; acc.y += v.y; acc.z += v.z; acc.w += v.w;
    }
  }
  #pragma unroll
  for(int off=16; off<=32; off<<=1){
    acc.x += __shfl_xor(acc.x, off, 64);
    acc.y += __shfl_xor(acc.y, off, 64);
    acc.z += __shfl_xor(acc.z, off, 64);
    acc.w += __shfl_xor(acc.w, off, 64);
  }
  float inv = inv_deg[n];
  const float4 b = *(const float4*)(b1 + (l15 << 2));
  float4 o;
  o.x = fmaxf(fmaf(acc.x, inv, b.x), 0.f);
  o.y = fmaxf(fmaf(acc.y, inv, b.y), 0.f);
  o.z = fmaxf(fmaf(acc.z, inv, b.z), 0.f);
  o.w = fmaxf(fmaf(acc.w, inv, b.w), 0.f);
  if(lane < 16) *(float4*)(h + ((size_t)n << 6) + (l15 << 2)) = o;
}

// ---------------- gather2: r[n] = |relu(inv*sum_nb z[nb] + b2) . Wp + bp| ----------------
__global__ __launch_bounds__(256) void k_gather2(const int* __restrict__ rowptr,
    const int* __restrict__ col, const float* __restrict__ inv_deg,
    const float* __restrict__ z_all, const float* __restrict__ b2,
    const float* __restrict__ Wp, const float* __restrict__ bp,
    float* __restrict__ r_all){
  int tid = threadIdx.x, lane = tid & 63;
  int n = (blockIdx.x << 2) + (tid >> 6);
  if(n >= NN) return;
  int cfg = blockIdx.y;
  const float* x = z_all + (size_t)cfg*NN*64;
  float* r_out = r_all + (size_t)cfg*NN;
  int l15 = lane & 15, g = lane >> 4;
  int kb = rowptr[n], ke = rowptr[n+1];
  float4 acc = {0.f,0.f,0.f,0.f};
  for(int base = kb; base < ke; base += 64){
    int kk = base + lane;
    int d = (kk < ke) ? col[kk] : 0;
    int cnt = min(64, ke - base);
    for(int k = g; k < cnt; k += 4){
      int dk = __shfl(d, k, 64);
      const float4 v = *(const float4*)(x + ((size_t)dk << 6) + (l15 << 2));
      acc.x += v.x; acc.y += v.y; acc.z += v.z; acc.w += v.w;
    }
  }
  #pragma unroll
  for(int off=16; off<=32; off<<=1){
    acc.x += __shfl_xor(acc.x, off, 64);
    acc.y += __shfl_xor(acc.y, off, 64);
    acc.z += __shfl_xor(acc.z, off, 64);
    acc.w += __shfl_xor(acc.w, off, 64);
  }
  float inv = inv_deg[n];
  const float4 b = *(const float4*)(b2 + (l15 << 2));
  const float4 wp = *(const float4*)(Wp + (l15 << 2));
  float p = fmaxf(fmaf(acc.x, inv, b.x), 0.f) * wp.x
          + fmaxf(fmaf(acc.y, inv, b.y), 0.f) * wp.y
          + fmaxf(fmaf(acc.z, inv, b.z), 0.f) * wp.z
          + fmaxf(fmaf(acc.w, inv, b.w), 0.f) * wp.w;
  #pragma unroll
  for(int off=1; off<16; off<<=1) p += __shfl_xor(p, off, 64);
  if(lane == 0) r_out[n] = fabsf(p + bp[0]);
}

// ---------------- pool ----------------
__global__ __launch_bounds__(256) void k_pool(const float* __restrict__ r_all,
    const int* __restrict__ off, float* __restrict__ out){
  __shared__ float red[256];
  int b = blockIdx.x;               // b = g*8 + c
  int g = b >> 3, c = b & 7;
  int lo = off[g], hi = off[g+1];
  float s = 0.f;
  for(int i = lo + (int)threadIdx.x; i < hi; i += 256) s += r_all[(size_t)c*NN + i];
  red[threadIdx.x] = s;
  __syncthreads();
  for(int w=128; w>0; w>>=1){
    if((int)threadIdx.x < w) red[threadIdx.x] += red[threadIdx.x + w];
    __syncthreads();
  }
  if(threadIdx.x == 0) out[b] = red[0];
}

extern "C" void kernel_launch(void* const* d_in, const int* in_sizes, int n_in,
                              void* d_out, int out_size, void* d_ws, size_t ws_size,
                              hipStream_t stream){
  (void)in_sizes; (void)n_in; (void)out_size; (void)ws_size;
  const float* feat = (const float*)d_in[0];
  const int*   eidx = (const int*)d_in[1];
  const int*   lens = (const int*)d_in[2];
  const float* emb  = (const float*)d_in[3];
  const float* W1   = (const float*)d_in[4];
  const float* b1   = (const float*)d_in[5];
  const float* W2   = (const float*)d_in[6];
  const float* b2   = (const float*)d_in[7];
  const float* Wp   = (const float*)d_in[8];
  const float* bp   = (const float*)d_in[9];
  float* out = (float*)d_out;
  const int* src = eidx;
  const int* dst = eidx + NE;

  char* ws = (char*)d_ws;
  size_t o = 0;
  auto alloc = [&](size_t bytes)->char*{ char* p = ws + o; o = (o + bytes + 255) & ~(size_t)255; return p; };
  int*   rowptr = (int*)  alloc((NN+1)*4);
  int*   cursor = (int*)  alloc((size_t)NN*4);
  int*   colx   = (int*)  alloc((size_t)NE*4);
  float* invd   = (float*)alloc((size_t)NN*4);
  int*   goff   = (int*)  alloc((NG+1)*4);
  float* eW1    = (float*)alloc(128*64*4);
  float* r_all  = (float*)alloc((size_t)NCFG*NN*4);
  float* z_all  = (float*)alloc((size_t)NCFG*NN*64*4);   // 204.8 MB
  float* h_all  = (float*)alloc((size_t)NCFG*NN*64*4);   // 204.8 MB

  hipMemsetAsync(cursor, 0, (size_t)NN*4, stream);
  k_hist   <<<(NE+255)/256, 256, 0, stream>>>(src, cursor, NE);
  k_scan   <<<1, 1024, 0, stream>>>(cursor, rowptr, invd, NN);
  k_fill   <<<(NE+255)/256, 256, 0, stream>>>(src, dst, cursor, colx, NE);
  k_embW1  <<<128, 64, 0, stream>>>(emb, W1, eW1);
  k_offsets<<<1, 64, 0, stream>>>(lens, goff);

  dim3 ggemm((NN+63)/64, NCFG);
  dim3 ggath((NN+3)/4, NCFG);
  k_gemm1  <<<ggemm, 256, 0, stream>>>(feat, eW1, W1, z_all);
  k_gather1<<<ggath, 256, 0, stream>>>(rowptr, colx, invd, z_all, b1, h_all);
  k_gemm2  <<<ggemm, 256, 0, stream>>>(h_all, W2, z_all);
  k_gather2<<<ggath, 256, 0, stream>>>(rowptr, colx, invd, z_all, b2, Wp, bp, r_all);
  k_pool   <<<NCFG*NG, 256, 0, stream>>>(r_all, goff, out);
}

// Round 4
// 537.202 us; speedup vs baseline: 3.2295x; 1.8336x over previous
//
#include <hip/hip_runtime.h>

#define NCFG 8
#define NN 100000
#define NE 400000
#define NG 10
#define FEAT 97

typedef __attribute__((ext_vector_type(8))) short bf16x8;
typedef __attribute__((ext_vector_type(4))) float f32x4;

__device__ inline short f2bf(float x){
  unsigned u = __float_as_uint(x);
  unsigned r = u + 0x7FFFu + ((u >> 16) & 1u);
  return (short)(r >> 16);
}
__device__ inline float bf2f(short h){
  return __uint_as_float(((unsigned)(unsigned short)h) << 16);
}

// ---------------- CSR build ----------------
__global__ void k_hist(const int* __restrict__ src, int* __restrict__ deg, int e_count){
  int e = blockIdx.x*blockDim.x + threadIdx.x;
  if(e < e_count) atomicAdd(&deg[src[e]], 1);
}

__global__ __launch_bounds__(1024) void k_scan(int* __restrict__ deg_cur, int* __restrict__ rowptr,
                                               float* __restrict__ inv_deg, int n){
  __shared__ int wsum[16];
  __shared__ int carry_s;
  int tid = threadIdx.x, lane = tid & 63, w = tid >> 6;
  if(tid == 0) carry_s = 0;
  for(int base = 0; base < n; base += 4096){
    int i0 = base + tid*4;
    int v0 = (i0+0 < n) ? deg_cur[i0+0] : 0;
    int v1 = (i0+1 < n) ? deg_cur[i0+1] : 0;
    int v2 = (i0+2 < n) ? deg_cur[i0+2] : 0;
    int v3 = (i0+3 < n) ? deg_cur[i0+3] : 0;
    int s = v0+v1+v2+v3;
    int x = s;
    #pragma unroll
    for(int off=1; off<64; off<<=1){
      int t = __shfl_up(x, off, 64);
      if(lane >= off) x += t;
    }
    __syncthreads();
    if(lane == 63) wsum[w] = x;
    __syncthreads();
    if(w == 0){
      int y = (lane < 16) ? wsum[lane] : 0;
      #pragma unroll
      for(int off=1; off<16; off<<=1){
        int t = __shfl_up(y, off, 64);
        if(lane >= off) y += t;
      }
      if(lane < 16) wsum[lane] = y;
    }
    __syncthreads();
    int waveoff = (w > 0) ? wsum[w-1] : 0;
    int carry = carry_s;
    int run = carry + waveoff + (x - s);
    if(i0+0 < n){ rowptr[i0+0]=run; deg_cur[i0+0]=run; inv_deg[i0+0]=1.0f/(float)max(v0,1); run+=v0; }
    if(i0+1 < n){ rowptr[i0+1]=run; deg_cur[i0+1]=run; inv_deg[i0+1]=1.0f/(float)max(v1,1); run+=v1; }
    if(i0+2 < n){ rowptr[i0+2]=run; deg_cur[i0+2]=run; inv_deg[i0+2]=1.0f/(float)max(v2,1); run+=v2; }
    if(i0+3 < n){ rowptr[i0+3]=run; deg_cur[i0+3]=run; inv_deg[i0+3]=1.0f/(float)max(v3,1); run+=v3; }
    __syncthreads();
    if(tid == 0) carry_s = carry + wsum[15];
  }
  if(tid == 0) rowptr[n] = carry_s;
}

__global__ void k_fill(const int* __restrict__ src, const int* __restrict__ dst,
                       int* __restrict__ cursor, int* __restrict__ col, int e_count){
  int e = blockIdx.x*blockDim.x + threadIdx.x;
  if(e < e_count){
    int pos = atomicAdd(&cursor[src[e]], 1);
    col[pos] = dst[e];
  }
}

__global__ void k_embW1(const float* __restrict__ emb, const float* __restrict__ W1,
                        float* __restrict__ embW1){
  int o = blockIdx.x, j = threadIdx.x;
  float s = 0.f;
  #pragma unroll
  for(int k=0;k<32;k++) s += emb[o*32+k] * W1[k*64+j];
  embW1[o*64+j] = s;
}

__global__ void k_offsets(const int* __restrict__ lengths, int* __restrict__ off){
  if(threadIdx.x == 0){
    int s = 0;
    for(int g=0; g<NG; g++){ off[g] = s; s += lengths[g]; }
    off[NG] = s;
  }
}

// ---------------- gemm1 (MFMA): z = feat[:,1:97] @ W1[32:,:] + embW1[op], z in bf16 ----------------
__global__ __launch_bounds__(256) void k_gemm1(const float* __restrict__ feat,
    const float* __restrict__ embW1, const float* __restrict__ W1,
    unsigned short* __restrict__ z_all){
  __shared__ short Bhi[3*4*64*8];
  __shared__ short Blo[3*4*64*8];
  __shared__ int ops[64];
  int tid = threadIdx.x;
  int nb = blockIdx.x * 64;
  int cfg = blockIdx.y;
  const float* f = feat + (size_t)cfg*NN*FEAT;
  unsigned short* z = z_all + (size_t)cfg*NN*64;

  for(int e = tid; e < 3*4*64*8; e += 256){
    int i = e & 7, l = (e >> 3) & 63, t = (e >> 9) & 3, kc = e >> 11;
    int k = kc*32 + ((l>>4)<<3) + i;
    int c = t*16 + (l & 15);
    float wv = W1[(32 + k)*64 + c];
    short h = f2bf(wv);
    Bhi[e] = h;
    Blo[e] = f2bf(wv - bf2f(h));
  }
  if(tid < 64){
    int node = nb + tid; if(node >= NN) node = NN-1;
    ops[tid] = (int)f[(size_t)node*FEAT];
  }
  __syncthreads();

  int w = tid >> 6, l = tid & 63;
  int row = nb + w*16 + (l & 15);
  if(row >= NN) row = NN-1;
  const float* frow = f + (size_t)row*FEAT + 1 + ((l>>4)<<3);

  f32x4 acc[4] = {{0,0,0,0},{0,0,0,0},{0,0,0,0},{0,0,0,0}};
  #pragma unroll
  for(int kc = 0; kc < 3; kc++){
    float a[8];
    #pragma unroll
    for(int i=0;i<8;i++) a[i] = frow[kc*32 + i];
    bf16x8 ahi, alo;
    #pragma unroll
    for(int i=0;i<8;i++){
      short h = f2bf(a[i]);
      ahi[i] = h;
      alo[i] = f2bf(a[i] - bf2f(h));
    }
    #pragma unroll
    for(int t=0;t<4;t++){
      const bf16x8 bh = *(const bf16x8*)&Bhi[((kc*4 + t)*64 + l)*8];
      const bf16x8 bl = *(const bf16x8*)&Blo[((kc*4 + t)*64 + l)*8];
      acc[t] = __builtin_amdgcn_mfma_f32_16x16x32_bf16(ahi, bh, acc[t], 0,0,0);
      acc[t] = __builtin_amdgcn_mfma_f32_16x16x32_bf16(alo, bh, acc[t], 0,0,0);
      acc[t] = __builtin_amdgcn_mfma_f32_16x16x32_bf16(ahi, bl, acc[t], 0,0,0);
    }
  }
  int r0 = w*16 + ((l>>4)<<2);
  int cb = l & 15;
  #pragma unroll
  for(int j=0;j<4;j++){
    int node = nb + r0 + j;
    if(node < NN){
      int op = ops[r0 + j];
      #pragma unroll
      for(int t=0;t<4;t++){
        int c = t*16 + cb;
        z[(size_t)node*64 + c] = (unsigned short)f2bf(acc[t][j] + embW1[op*64 + c]);
      }
    }
  }
}

// ---------------- gemm2 (MFMA): z = h @ W2 (h bf16 exact -> 2 MFMA/tile), z bf16 ----------------
__global__ __launch_bounds__(256) void k_gemm2(const unsigned short* __restrict__ h_all,
    const float* __restrict__ W2, unsigned short* __restrict__ z_all){
  __shared__ short Bhi[2*4*64*8];
  __shared__ short Blo[2*4*64*8];
  int tid = threadIdx.x;
  int nb = blockIdx.x * 64;
  int cfg = blockIdx.y;
  const unsigned short* hsrc = h_all + (size_t)cfg*NN*64;
  unsigned short* z = z_all + (size_t)cfg*NN*64;

  for(int e = tid; e < 2*4*64*8; e += 256){
    int i = e & 7, l = (e >> 3) & 63, t = (e >> 9) & 3, kc = e >> 11;
    int k = kc*32 + ((l>>4)<<3) + i;
    int c = t*16 + (l & 15);
    float wv = W2[k*64 + c];
    short h = f2bf(wv);
    Bhi[e] = h;
    Blo[e] = f2bf(wv - bf2f(h));
  }
  __syncthreads();

  int w = tid >> 6, l = tid & 63;
  int row = nb + w*16 + (l & 15);
  if(row >= NN) row = NN-1;
  const unsigned short* hrow = hsrc + (size_t)row*64 + ((l>>4)<<3);

  f32x4 acc[4] = {{0,0,0,0},{0,0,0,0},{0,0,0,0},{0,0,0,0}};
  #pragma unroll
  for(int kc = 0; kc < 2; kc++){
    const bf16x8 a = *(const bf16x8*)(hrow + kc*32);
    #pragma unroll
    for(int t=0;t<4;t++){
      const bf16x8 bh = *(const bf16x8*)&Bhi[((kc*4 + t)*64 + l)*8];
      const bf16x8 bl = *(const bf16x8*)&Blo[((kc*4 + t)*64 + l)*8];
      acc[t] = __builtin_amdgcn_mfma_f32_16x16x32_bf16(a, bh, acc[t], 0,0,0);
      acc[t] = __builtin_amdgcn_mfma_f32_16x16x32_bf16(a, bl, acc[t], 0,0,0);
    }
  }
  int r0 = w*16 + ((l>>4)<<2);
  int cb = l & 15;
  #pragma unroll
  for(int j=0;j<4;j++){
    int node = nb + r0 + j;
    if(node < NN){
      #pragma unroll
      for(int t=0;t<4;t++){
        z[(size_t)node*64 + t*16 + cb] = (unsigned short)f2bf(acc[t][j]);
      }
    }
  }
}

// ---------------- gather1: h[c][n] = relu(inv*sum_nb z[c][nb] + b1), all cfgs per wave ----------------
// wave = 8 cfg-groups x 8 lanes; each lane owns 8 bf16 cols of its cfg's row
__global__ __launch_bounds__(256) void k_gather1(const int* __restrict__ rowptr,
    const int* __restrict__ col, const float* __restrict__ inv_deg,
    const unsigned short* __restrict__ z_all, const float* __restrict__ b1,
    unsigned short* __restrict__ h_all){
  int tid = threadIdx.x, lane = tid & 63;
  int n = (blockIdx.x << 2) + (tid >> 6);
  if(n >= NN) return;
  int cfg = lane >> 3, sub = lane & 7;
  const unsigned short* zc = z_all + (size_t)cfg*NN*64 + sub*8;
  int kb = __builtin_amdgcn_readfirstlane(rowptr[n]);
  int ke = __builtin_amdgcn_readfirstlane(rowptr[n+1]);
  float acc[8] = {0,0,0,0,0,0,0,0};
  for(int k = kb; k < ke; k++){
    int d = col[k];
    const bf16x8 v = *(const bf16x8*)(zc + ((size_t)d << 6));
    #pragma unroll
    for(int i=0;i<8;i++) acc[i] += bf2f(v[i]);
  }
  float inv = inv_deg[n];
  const float4 bA = *(const float4*)(b1 + sub*8);
  const float4 bB = *(const float4*)(b1 + sub*8 + 4);
  float bv[8] = {bA.x,bA.y,bA.z,bA.w,bB.x,bB.y,bB.z,bB.w};
  bf16x8 o;
  #pragma unroll
  for(int i=0;i<8;i++) o[i] = f2bf(fmaxf(fmaf(acc[i], inv, bv[i]), 0.f));
  *(bf16x8*)(h_all + (size_t)cfg*NN*64 + ((size_t)n << 6) + sub*8) = o;
}

// ---------------- gather2: r[c][n] = |relu(inv*sum_nb z[c][nb] + b2) . Wp + bp| ----------------
__global__ __launch_bounds__(256) void k_gather2(const int* __restrict__ rowptr,
    const int* __restrict__ col, const float* __restrict__ inv_deg,
    const unsigned short* __restrict__ z_all, const float* __restrict__ b2,
    const float* __restrict__ Wp, const float* __restrict__ bp,
    float* __restrict__ r_all){
  int tid = threadIdx.x, lane = tid & 63;
  int n = (blockIdx.x << 2) + (tid >> 6);
  if(n >= NN) return;
  int cfg = lane >> 3, sub = lane & 7;
  const unsigned short* zc = z_all + (size_t)cfg*NN*64 + sub*8;
  int kb = __builtin_amdgcn_readfirstlane(rowptr[n]);
  int ke = __builtin_amdgcn_readfirstlane(rowptr[n+1]);
  float acc[8] = {0,0,0,0,0,0,0,0};
  for(int k = kb; k < ke; k++){
    int d = col[k];
    const bf16x8 v = *(const bf16x8*)(zc + ((size_t)d << 6));
    #pragma unroll
    for(int i=0;i<8;i++) acc[i] += bf2f(v[i]);
  }
  float inv = inv_deg[n];
  const float4 bA = *(const float4*)(b2 + sub*8);
  const float4 bB = *(const float4*)(b2 + sub*8 + 4);
  const float4 wA = *(const float4*)(Wp + sub*8);
  const float4 wB = *(const float4*)(Wp + sub*8 + 4);
  float bv[8] = {bA.x,bA.y,bA.z,bA.w,bB.x,bB.y,bB.z,bB.w};
  float wv[8] = {wA.x,wA.y,wA.z,wA.w,wB.x,wB.y,wB.z,wB.w};
  float p = 0.f;
  #pragma unroll
  for(int i=0;i<8;i++)
    p += fmaxf(fmaf(acc[i], inv, bv[i]), 0.f) * wv[i];
  p += __shfl_xor(p, 1, 64);
  p += __shfl_xor(p, 2, 64);
  p += __shfl_xor(p, 4, 64);
  if(sub == 0) r_all[(size_t)cfg*NN + n] = fabsf(p + bp[0]);
}

// ---------------- pool ----------------
__global__ __launch_bounds__(256) void k_pool(const float* __restrict__ r_all,
    const int* __restrict__ off, float* __restrict__ out){
  __shared__ float red[256];
  int b = blockIdx.x;               // b = g*8 + c
  int g = b >> 3, c = b & 7;
  int lo = off[g], hi = off[g+1];
  float s = 0.f;
  for(int i = lo + (int)threadIdx.x; i < hi; i += 256) s += r_all[(size_t)c*NN + i];
  red[threadIdx.x] = s;
  __syncthreads();
  for(int w=128; w>0; w>>=1){
    if((int)threadIdx.x < w) red[threadIdx.x] += red[threadIdx.x + w];
    __syncthreads();
  }
  if(threadIdx.x == 0) out[b] = red[0];
}

extern "C" void kernel_launch(void* const* d_in, const int* in_sizes, int n_in,
                              void* d_out, int out_size, void* d_ws, size_t ws_size,
                              hipStream_t stream){
  (void)in_sizes; (void)n_in; (void)out_size; (void)ws_size;
  const float* feat = (const float*)d_in[0];
  const int*   eidx = (const int*)d_in[1];
  const int*   lens = (const int*)d_in[2];
  const float* emb  = (const float*)d_in[3];
  const float* W1   = (const float*)d_in[4];
  const float* b1   = (const float*)d_in[5];
  const float* W2   = (const float*)d_in[6];
  const float* b2   = (const float*)d_in[7];
  const float* Wp   = (const float*)d_in[8];
  const float* bp   = (const float*)d_in[9];
  float* out = (float*)d_out;
  const int* src = eidx;
  const int* dst = eidx + NE;

  char* ws = (char*)d_ws;
  size_t o = 0;
  auto alloc = [&](size_t bytes)->char*{ char* p = ws + o; o = (o + bytes + 255) & ~(size_t)255; return p; };
  int*   rowptr = (int*)  alloc((NN+1)*4);
  int*   cursor = (int*)  alloc((size_t)NN*4);
  int*   colx   = (int*)  alloc((size_t)NE*4);
  float* invd   = (float*)alloc((size_t)NN*4);
  int*   goff   = (int*)  alloc((NG+1)*4);
  float* eW1    = (float*)alloc(128*64*4);
  float* r_all  = (float*)alloc((size_t)NCFG*NN*4);
  unsigned short* z_all = (unsigned short*)alloc((size_t)NCFG*NN*64*2);  // 102.4 MB
  unsigned short* h_all = (unsigned short*)alloc((size_t)NCFG*NN*64*2);  // 102.4 MB

  hipMemsetAsync(cursor, 0, (size_t)NN*4, stream);
  k_hist   <<<(NE+255)/256, 256, 0, stream>>>(src, cursor, NE);
  k_scan   <<<1, 1024, 0, stream>>>(cursor, rowptr, invd, NN);
  k_fill   <<<(NE+255)/256, 256, 0, stream>>>(src, dst, cursor, colx, NE);
  k_embW1  <<<128, 64, 0, stream>>>(emb, W1, eW1);
  k_offsets<<<1, 64, 0, stream>>>(lens, goff);

  dim3 ggemm((NN+63)/64, NCFG);
  dim3 ggath((NN+3)/4, 1);
  k_gemm1  <<<ggemm, 256, 0, stream>>>(feat, eW1, W1, z_all);
  k_gather1<<<ggath, 256, 0, stream>>>(rowptr, colx, invd, z_all, b1, h_all);
  k_gemm2  <<<ggemm, 256, 0, stream>>>(h_all, W2, z_all);
  k_gather2<<<ggath, 256, 0, stream>>>(rowptr, colx, invd, z_all, b2, Wp, bp, r_all);
  k_pool   <<<NCFG*NG, 256, 0, stream>>>(r_all, goff, out);
}

// Round 5
// 479.087 us; speedup vs baseline: 3.6212x; 1.1213x over previous
//
#include <hip/hip_runtime.h>

#define NCFG 8
#define NN 100000
#define NE 400000
#define NG 10
#define FEAT 97

typedef __attribute__((ext_vector_type(8))) short bf16x8;
typedef __attribute__((ext_vector_type(4))) float f32x4;

__device__ inline short f2bf(float x){
  unsigned u = __float_as_uint(x);
  unsigned r = u + 0x7FFFu + ((u >> 16) & 1u);
  return (short)(r >> 16);
}
__device__ inline float bf2f(short h){
  return __uint_as_float(((unsigned)(unsigned short)h) << 16);
}

// ---------------- CSR build ----------------
__global__ void k_hist(const int* __restrict__ src, int* __restrict__ deg, int e_count){
  int e = blockIdx.x*blockDim.x + threadIdx.x;
  if(e < e_count) atomicAdd(&deg[src[e]], 1);
}

__global__ __launch_bounds__(1024) void k_scan(int* __restrict__ deg_cur, int* __restrict__ rowptr,
                                               float* __restrict__ inv_deg, int n){
  __shared__ int wsum[16];
  __shared__ int carry_s;
  int tid = threadIdx.x, lane = tid & 63, w = tid >> 6;
  if(tid == 0) carry_s = 0;
  for(int base = 0; base < n; base += 4096){
    int i0 = base + tid*4;
    int v0 = (i0+0 < n) ? deg_cur[i0+0] : 0;
    int v1 = (i0+1 < n) ? deg_cur[i0+1] : 0;
    int v2 = (i0+2 < n) ? deg_cur[i0+2] : 0;
    int v3 = (i0+3 < n) ? deg_cur[i0+3] : 0;
    int s = v0+v1+v2+v3;
    int x = s;
    #pragma unroll
    for(int off=1; off<64; off<<=1){
      int t = __shfl_up(x, off, 64);
      if(lane >= off) x += t;
    }
    __syncthreads();
    if(lane == 63) wsum[w] = x;
    __syncthreads();
    if(w == 0){
      int y = (lane < 16) ? wsum[lane] : 0;
      #pragma unroll
      for(int off=1; off<16; off<<=1){
        int t = __shfl_up(y, off, 64);
        if(lane >= off) y += t;
      }
      if(lane < 16) wsum[lane] = y;
    }
    __syncthreads();
    int waveoff = (w > 0) ? wsum[w-1] : 0;
    int carry = carry_s;
    int run = carry + waveoff + (x - s);
    if(i0+0 < n){ rowptr[i0+0]=run; deg_cur[i0+0]=run; inv_deg[i0+0]=1.0f/(float)max(v0,1); run+=v0; }
    if(i0+1 < n){ rowptr[i0+1]=run; deg_cur[i0+1]=run; inv_deg[i0+1]=1.0f/(float)max(v1,1); run+=v1; }
    if(i0+2 < n){ rowptr[i0+2]=run; deg_cur[i0+2]=run; inv_deg[i0+2]=1.0f/(float)max(v2,1); run+=v2; }
    if(i0+3 < n){ rowptr[i0+3]=run; deg_cur[i0+3]=run; inv_deg[i0+3]=1.0f/(float)max(v3,1); run+=v3; }
    __syncthreads();
    if(tid == 0) carry_s = carry + wsum[15];
  }
  if(tid == 0) rowptr[n] = carry_s;
}

__global__ void k_fill(const int* __restrict__ src, const int* __restrict__ dst,
                       int* __restrict__ cursor, int* __restrict__ col, int e_count){
  int e = blockIdx.x*blockDim.x + threadIdx.x;
  if(e < e_count){
    int pos = atomicAdd(&cursor[src[e]], 1);
    col[pos] = dst[e];
  }
}

__global__ void k_embW1(const float* __restrict__ emb, const float* __restrict__ W1,
                        float* __restrict__ embW1){
  int o = blockIdx.x, j = threadIdx.x;
  float s = 0.f;
  #pragma unroll
  for(int k=0;k<32;k++) s += emb[o*32+k] * W1[k*64+j];
  embW1[o*64+j] = s;
}

__global__ void k_offsets(const int* __restrict__ lengths, int* __restrict__ off){
  if(threadIdx.x == 0){
    int s = 0;
    for(int g=0; g<NG; g++){ off[g] = s; s += lengths[g]; }
    off[NG] = s;
  }
}

// ---------------- prep B fragments (once): frag-order [kc][t][lane][8], bf16 hi/lo ----------------
__global__ __launch_bounds__(256) void k_prepB(const float* __restrict__ W1, const float* __restrict__ W2,
    short* __restrict__ bW1hi, short* __restrict__ bW1lo,
    short* __restrict__ bW2hi, short* __restrict__ bW2lo){
  int e = blockIdx.x*256 + threadIdx.x;
  if(e < 3*4*64*8){
    int i=e&7, l=(e>>3)&63, t=(e>>9)&3, kc=e>>11;
    int k=kc*32+((l>>4)<<3)+i, c=t*16+(l&15);
    float wv = W1[(32+k)*64+c];
    short h=f2bf(wv); bW1hi[e]=h; bW1lo[e]=f2bf(wv-bf2f(h));
  }
  if(e < 2*4*64*8){
    int i=e&7, l=(e>>3)&63, t=(e>>9)&3, kc=e>>11;
    int k=kc*32+((l>>4)<<3)+i, c=t*16+(l&15);
    float wv = W2[k*64+c];
    short h=f2bf(wv); bW2hi[e]=h; bW2lo[e]=f2bf(wv-bf2f(h));
  }
}

// ---------------- gemm1 (MFMA): z = feat[:,1:97] @ W1[32:,:] + embW1[op], z bf16 [node][cfg][64] ----------------
__global__ __launch_bounds__(256) void k_gemm1(const float* __restrict__ feat,
    const float* __restrict__ embW1,
    const short* __restrict__ bW1hi, const short* __restrict__ bW1lo,
    unsigned short* __restrict__ z_all){
  __shared__ float lds_f[64*FEAT];      // 24832 B, flat [row][97]
  int tid = threadIdx.x;
  int nb = blockIdx.x * 64;
  int cfg = blockIdx.y;
  const float* f = feat + (size_t)cfg*NN*FEAT;
  const float* gsrc = f + (size_t)nb*FEAT;  // 16B-aligned (64*97*4 = 24832)
  int nvalid = (min(64, NN-nb))*FEAT;

  // coalesced float4 staging: 64*97 = 6208 floats = 1552 float4 exactly
  for(int idx = tid; idx < 1552; idx += 256){
    int base = idx*4;
    float4 v;
    if(base + 3 < nvalid) v = *(const float4*)(gsrc + base);
    else {
      v.x = (base+0 < nvalid) ? gsrc[base+0] : 0.f;
      v.y = (base+1 < nvalid) ? gsrc[base+1] : 0.f;
      v.z = (base+2 < nvalid) ? gsrc[base+2] : 0.f;
      v.w = (base+3 < nvalid) ? gsrc[base+3] : 0.f;
    }
    *(float4*)&lds_f[base] = v;
  }
  __syncthreads();

  int w = tid >> 6, l = tid & 63;
  int lrow = w*16 + (l & 15);           // block-local A row
  int g8 = (l >> 4) << 3;               // k-octet offset

  f32x4 acc[4] = {{0,0,0,0},{0,0,0,0},{0,0,0,0},{0,0,0,0}};
  #pragma unroll
  for(int kc = 0; kc < 3; kc++){
    const float* ap = &lds_f[lrow*FEAT + 1 + g8 + kc*32];
    bf16x8 ahi, alo;
    #pragma unroll
    for(int i=0;i<8;i++){
      float a = ap[i];
      short h = f2bf(a);
      ahi[i] = h;
      alo[i] = f2bf(a - bf2f(h));
    }
    #pragma unroll
    for(int t=0;t<4;t++){
      const bf16x8 bh = *(const bf16x8*)&bW1hi[((kc*4 + t)*64 + l)*8];
      const bf16x8 bl = *(const bf16x8*)&bW1lo[((kc*4 + t)*64 + l)*8];
      acc[t] = __builtin_amdgcn_mfma_f32_16x16x32_bf16(ahi, bh, acc[t], 0,0,0);
      acc[t] = __builtin_amdgcn_mfma_f32_16x16x32_bf16(alo, bh, acc[t], 0,0,0);
      acc[t] = __builtin_amdgcn_mfma_f32_16x16x32_bf16(ahi, bl, acc[t], 0,0,0);
    }
  }
  int r0 = w*16 + ((l>>4)<<2);
  int cb = l & 15;
  #pragma unroll
  for(int j=0;j<4;j++){
    int node = nb + r0 + j;
    if(node < NN){
      int op = (int)lds_f[(r0+j)*FEAT];
      #pragma unroll
      for(int t=0;t<4;t++){
        int c = t*16 + cb;
        z_all[((size_t)node*NCFG + cfg)*64 + c] = (unsigned short)f2bf(acc[t][j] + embW1[op*64 + c]);
      }
    }
  }
}

// ---------------- gemm2 (MFMA): z = h @ W2, bf16 [node][cfg][64] ----------------
__global__ __launch_bounds__(256) void k_gemm2(const unsigned short* __restrict__ h_all,
    const short* __restrict__ bW2hi, const short* __restrict__ bW2lo,
    unsigned short* __restrict__ z_all){
  int tid = threadIdx.x;
  int nb = blockIdx.x * 64;
  int cfg = blockIdx.y;

  int w = tid >> 6, l = tid & 63;
  int row = nb + w*16 + (l & 15);
  if(row >= NN) row = NN-1;
  const unsigned short* hrow = h_all + ((size_t)row*NCFG + cfg)*64 + ((l>>4)<<3);

  f32x4 acc[4] = {{0,0,0,0},{0,0,0,0},{0,0,0,0},{0,0,0,0}};
  #pragma unroll
  for(int kc = 0; kc < 2; kc++){
    const bf16x8 a = *(const bf16x8*)(hrow + kc*32);
    #pragma unroll
    for(int t=0;t<4;t++){
      const bf16x8 bh = *(const bf16x8*)&bW2hi[((kc*4 + t)*64 + l)*8];
      const bf16x8 bl = *(const bf16x8*)&bW2lo[((kc*4 + t)*64 + l)*8];
      acc[t] = __builtin_amdgcn_mfma_f32_16x16x32_bf16(a, bh, acc[t], 0,0,0);
      acc[t] = __builtin_amdgcn_mfma_f32_16x16x32_bf16(a, bl, acc[t], 0,0,0);
    }
  }
  int r0 = w*16 + ((l>>4)<<2);
  int cb = l & 15;
  #pragma unroll
  for(int j=0;j<4;j++){
    int node = nb + r0 + j;
    if(node < NN){
      #pragma unroll
      for(int t=0;t<4;t++){
        z_all[((size_t)node*NCFG + cfg)*64 + t*16 + cb] = (unsigned short)f2bf(acc[t][j]);
      }
    }
  }
}

// ---------------- gather1: h[n][c] = relu(inv*sum_nb z[nb][c] + b1) ----------------
// wave per node; z row [cfg][64] interleaved -> one coalesced 1KB load per edge
__global__ __launch_bounds__(256) void k_gather1(const int* __restrict__ rowptr,
    const int* __restrict__ col, const float* __restrict__ inv_deg,
    const unsigned short* __restrict__ z_all, const float* __restrict__ b1,
    unsigned short* __restrict__ h_all){
  int tid = threadIdx.x, lane = tid & 63;
  int n = (blockIdx.x << 2) + (tid >> 6);
  if(n >= NN) return;
  int sub = lane & 7;
  const unsigned short* zl = z_all + lane*8;
  int kb = __builtin_amdgcn_readfirstlane(rowptr[n]);
  int ke = __builtin_amdgcn_readfirstlane(rowptr[n+1]);
  float acc[8] = {0,0,0,0,0,0,0,0};
  for(int k = kb; k < ke; k++){
    int d = __builtin_amdgcn_readfirstlane(col[k]);
    const bf16x8 v = *(const bf16x8*)(zl + (size_t)d*512);
    #pragma unroll
    for(int i=0;i<8;i++) acc[i] += bf2f(v[i]);
  }
  float inv = inv_deg[n];
  const float4 bA = *(const float4*)(b1 + sub*8);
  const float4 bB = *(const float4*)(b1 + sub*8 + 4);
  float bv[8] = {bA.x,bA.y,bA.z,bA.w,bB.x,bB.y,bB.z,bB.w};
  bf16x8 o;
  #pragma unroll
  for(int i=0;i<8;i++) o[i] = f2bf(fmaxf(fmaf(acc[i], inv, bv[i]), 0.f));
  *(bf16x8*)(h_all + (size_t)n*512 + lane*8) = o;
}

// ---------------- gather2: r[c][n] = |relu(inv*sum_nb z[nb][c] + b2) . Wp + bp| ----------------
__global__ __launch_bounds__(256) void k_gather2(const int* __restrict__ rowptr,
    const int* __restrict__ col, const float* __restrict__ inv_deg,
    const unsigned short* __restrict__ z_all, const float* __restrict__ b2,
    const float* __restrict__ Wp, const float* __restrict__ bp,
    float* __restrict__ r_all){
  int tid = threadIdx.x, lane = tid & 63;
  int n = (blockIdx.x << 2) + (tid >> 6);
  if(n >= NN) return;
  int cfg = lane >> 3, sub = lane & 7;
  const unsigned short* zl = z_all + lane*8;
  int kb = __builtin_amdgcn_readfirstlane(rowptr[n]);
  int ke = __builtin_amdgcn_readfirstlane(rowptr[n+1]);
  float acc[8] = {0,0,0,0,0,0,0,0};
  for(int k = kb; k < ke; k++){
    int d = __builtin_amdgcn_readfirstlane(col[k]);
    const bf16x8 v = *(const bf16x8*)(zl + (size_t)d*512);
    #pragma unroll
    for(int i=0;i<8;i++) acc[i] += bf2f(v[i]);
  }
  float inv = inv_deg[n];
  const float4 bA = *(const float4*)(b2 + sub*8);
  const float4 bB = *(const float4*)(b2 + sub*8 + 4);
  const float4 wA = *(const float4*)(Wp + sub*8);
  const float4 wB = *(const float4*)(Wp + sub*8 + 4);
  float bv[8] = {bA.x,bA.y,bA.z,bA.w,bB.x,bB.y,bB.z,bB.w};
  float wv[8] = {wA.x,wA.y,wA.z,wA.w,wB.x,wB.y,wB.z,wB.w};
  float p = 0.f;
  #pragma unroll
  for(int i=0;i<8;i++)
    p += fmaxf(fmaf(acc[i], inv, bv[i]), 0.f) * wv[i];
  p += __shfl_xor(p, 1, 64);
  p += __shfl_xor(p, 2, 64);
  p += __shfl_xor(p, 4, 64);
  if(sub == 0) r_all[(size_t)cfg*NN + n] = fabsf(p + bp[0]);
}

// ---------------- pool ----------------
__global__ __launch_bounds__(256) void k_pool(const float* __restrict__ r_all,
    const int* __restrict__ off, float* __restrict__ out){
  __shared__ float red[256];
  int b = blockIdx.x;               // b = g*8 + c
  int g = b >> 3, c = b & 7;
  int lo = off[g], hi = off[g+1];
  float s = 0.f;
  for(int i = lo + (int)threadIdx.x; i < hi; i += 256) s += r_all[(size_t)c*NN + i];
  red[threadIdx.x] = s;
  __syncthreads();
  for(int w=128; w>0; w>>=1){
    if((int)threadIdx.x < w) red[threadIdx.x] += red[threadIdx.x + w];
    __syncthreads();
  }
  if(threadIdx.x == 0) out[b] = red[0];
}

extern "C" void kernel_launch(void* const* d_in, const int* in_sizes, int n_in,
                              void* d_out, int out_size, void* d_ws, size_t ws_size,
                              hipStream_t stream){
  (void)in_sizes; (void)n_in; (void)out_size; (void)ws_size;
  const float* feat = (const float*)d_in[0];
  const int*   eidx = (const int*)d_in[1];
  const int*   lens = (const int*)d_in[2];
  const float* emb  = (const float*)d_in[3];
  const float* W1   = (const float*)d_in[4];
  const float* b1   = (const float*)d_in[5];
  const float* W2   = (const float*)d_in[6];
  const float* b2   = (const float*)d_in[7];
  const float* Wp   = (const float*)d_in[8];
  const float* bp   = (const float*)d_in[9];
  float* out = (float*)d_out;
  const int* src = eidx;
  const int* dst = eidx + NE;

  char* ws = (char*)d_ws;
  size_t o = 0;
  auto alloc = [&](size_t bytes)->char*{ char* p = ws + o; o = (o + bytes + 255) & ~(size_t)255; return p; };
  int*   rowptr = (int*)  alloc((NN+1)*4);
  int*   cursor = (int*)  alloc((size_t)NN*4);
  int*   colx   = (int*)  alloc((size_t)NE*4);
  float* invd   = (float*)alloc((size_t)NN*4);
  int*   goff   = (int*)  alloc((NG+1)*4);
  float* eW1    = (float*)alloc(128*64*4);
  short* bW1hi  = (short*)alloc(3*4*64*8*2);
  short* bW1lo  = (short*)alloc(3*4*64*8*2);
  short* bW2hi  = (short*)alloc(2*4*64*8*2);
  short* bW2lo  = (short*)alloc(2*4*64*8*2);
  float* r_all  = (float*)alloc((size_t)NCFG*NN*4);
  unsigned short* z_all = (unsigned short*)alloc((size_t)NN*NCFG*64*2);  // 102.4 MB, [node][cfg][64]
  unsigned short* h_all = (unsigned short*)alloc((size_t)NN*NCFG*64*2);  // 102.4 MB

  hipMemsetAsync(cursor, 0, (size_t)NN*4, stream);
  k_hist   <<<(NE+255)/256, 256, 0, stream>>>(src, cursor, NE);
  k_scan   <<<1, 1024, 0, stream>>>(cursor, rowptr, invd, NN);
  k_fill   <<<(NE+255)/256, 256, 0, stream>>>(src, dst, cursor, colx, NE);
  k_embW1  <<<128, 64, 0, stream>>>(emb, W1, eW1);
  k_prepB  <<<24, 256, 0, stream>>>(W1, W2, bW1hi, bW1lo, bW2hi, bW2lo);
  k_offsets<<<1, 64, 0, stream>>>(lens, goff);

  dim3 ggemm((NN+63)/64, NCFG);
  dim3 ggath((NN+3)/4, 1);
  k_gemm1  <<<ggemm, 256, 0, stream>>>(feat, eW1, bW1hi, bW1lo, z_all);
  k_gather1<<<ggath, 256, 0, stream>>>(rowptr, colx, invd, z_all, b1, h_all);
  k_gemm2  <<<ggemm, 256, 0, stream>>>(h_all, bW2hi, bW2lo, z_all);
  k_gather2<<<ggath, 256, 0, stream>>>(rowptr, colx, invd, z_all, b2, Wp, bp, r_all);
  k_pool   <<<NCFG*NG, 256, 0, stream>>>(r_all, goff, out);
}

// Round 6
// 367.864 us; speedup vs baseline: 4.7161x; 1.3023x over previous
//
#include <hip/hip_runtime.h>

#define NCFG 8
#define NN 100000
#define NE 400000
#define NG 10
#define FEAT 97
#define SCAN_BLOCKS 25   // ceil(NN/4096)

typedef __attribute__((ext_vector_type(8))) short bf16x8;
typedef __attribute__((ext_vector_type(4))) float f32x4;

__device__ inline short f2bf(float x){
  unsigned u = __float_as_uint(x);
  unsigned r = u + 0x7FFFu + ((u >> 16) & 1u);
  return (short)(r >> 16);
}
__device__ inline float bf2f(short h){
  return __uint_as_float(((unsigned)(unsigned short)h) << 16);
}

// ---------------- CSR build ----------------
__global__ void k_hist(const int* __restrict__ src, int* __restrict__ deg, int e_count){
  int e = blockIdx.x*blockDim.x + threadIdx.x;
  if(e < e_count) atomicAdd(&deg[src[e]], 1);
}

// block sums: 25 blocks x 1024 thr x 4 elems
__global__ __launch_bounds__(1024) void k_scanA(const int* __restrict__ deg,
    int* __restrict__ partial, int n){
  __shared__ int ws[16];
  int tid = threadIdx.x;
  int i0 = blockIdx.x*4096 + tid*4;
  int s = 0;
  #pragma unroll
  for(int i=0;i<4;i++) if(i0+i < n) s += deg[i0+i];
  #pragma unroll
  for(int off=1; off<64; off<<=1) s += __shfl_xor(s, off, 64);
  if((tid & 63) == 0) ws[tid >> 6] = s;
  __syncthreads();
  if(tid < 16){
    int v = ws[tid];
    #pragma unroll
    for(int off=1; off<16; off<<=1) v += __shfl_xor(v, off, 16);
    if(tid == 0) partial[blockIdx.x] = v;
  }
}

// scan 25 partials -> exclusive; write rowptr[n]=total
__global__ void k_scanB(int* __restrict__ partial, int* __restrict__ rowptr, int nb, int n){
  int tid = threadIdx.x;   // 64
  int v = (tid < nb) ? partial[tid] : 0;
  int x = v;
  #pragma unroll
  for(int off=1; off<64; off<<=1){
    int t = __shfl_up(x, off, 64);
    if(tid >= off) x += t;
  }
  if(tid < nb) partial[tid] = x - v;
  if(tid == nb-1) rowptr[n] = x;
}

// local exclusive scan + block offset; write rowptr/cursor/inv_deg
__global__ __launch_bounds__(1024) void k_scanC(int* __restrict__ deg_cur,
    const int* __restrict__ partial, int* __restrict__ rowptr,
    float* __restrict__ inv_deg, int n){
  __shared__ int wsum[16];
  int tid = threadIdx.x, lane = tid & 63, w = tid >> 6;
  int i0 = blockIdx.x*4096 + tid*4;
  int v0 = (i0+0 < n) ? deg_cur[i0+0] : 0;
  int v1 = (i0+1 < n) ? deg_cur[i0+1] : 0;
  int v2 = (i0+2 < n) ? deg_cur[i0+2] : 0;
  int v3 = (i0+3 < n) ? deg_cur[i0+3] : 0;
  int s = v0+v1+v2+v3;
  int x = s;
  #pragma unroll
  for(int off=1; off<64; off<<=1){
    int t = __shfl_up(x, off, 64);
    if(lane >= off) x += t;
  }
  if(lane == 63) wsum[w] = x;
  __syncthreads();
  if(w == 0){
    int y = (lane < 16) ? wsum[lane] : 0;
    #pragma unroll
    for(int off=1; off<16; off<<=1){
      int t = __shfl_up(y, off, 64);
      if(lane >= off) y += t;
    }
    if(lane < 16) wsum[lane] = y;
  }
  __syncthreads();
  int waveoff = (w > 0) ? wsum[w-1] : 0;
  int run = partial[blockIdx.x] + waveoff + (x - s);
  if(i0+0 < n){ rowptr[i0+0]=run; deg_cur[i0+0]=run; inv_deg[i0+0]=1.0f/(float)max(v0,1); run+=v0; }
  if(i0+1 < n){ rowptr[i0+1]=run; deg_cur[i0+1]=run; inv_deg[i0+1]=1.0f/(float)max(v1,1); run+=v1; }
  if(i0+2 < n){ rowptr[i0+2]=run; deg_cur[i0+2]=run; inv_deg[i0+2]=1.0f/(float)max(v2,1); run+=v2; }
  if(i0+3 < n){ rowptr[i0+3]=run; deg_cur[i0+3]=run; inv_deg[i0+3]=1.0f/(float)max(v3,1); run+=v3; }
}

__global__ void k_fill(const int* __restrict__ src, const int* __restrict__ dst,
                       int* __restrict__ cursor, int* __restrict__ col, int e_count){
  int e = blockIdx.x*blockDim.x + threadIdx.x;
  if(e < e_count){
    int pos = atomicAdd(&cursor[src[e]], 1);
    col[pos] = dst[e];
  }
}

__global__ void k_embW1(const float* __restrict__ emb, const float* __restrict__ W1,
                        float* __restrict__ embW1){
  int o = blockIdx.x, j = threadIdx.x;
  float s = 0.f;
  #pragma unroll
  for(int k=0;k<32;k++) s += emb[o*32+k] * W1[k*64+j];
  embW1[o*64+j] = s;
}

__global__ void k_offsets(const int* __restrict__ lengths, int* __restrict__ off){
  if(threadIdx.x == 0){
    int s = 0;
    for(int g=0; g<NG; g++){ off[g] = s; s += lengths[g]; }
    off[NG] = s;
  }
}

// ---------------- prep B fragments (once): frag-order [kc][t][lane][8], bf16 hi/lo ----------------
__global__ __launch_bounds__(256) void k_prepB(const float* __restrict__ W1, const float* __restrict__ W2,
    short* __restrict__ bW1hi, short* __restrict__ bW1lo,
    short* __restrict__ bW2hi, short* __restrict__ bW2lo){
  int e = blockIdx.x*256 + threadIdx.x;
  if(e < 3*4*64*8){
    int i=e&7, l=(e>>3)&63, t=(e>>9)&3, kc=e>>11;
    int k=kc*32+((l>>4)<<3)+i, c=t*16+(l&15);
    float wv = W1[(32+k)*64+c];
    short h=f2bf(wv); bW1hi[e]=h; bW1lo[e]=f2bf(wv-bf2f(h));
  }
  if(e < 2*4*64*8){
    int i=e&7, l=(e>>3)&63, t=(e>>9)&3, kc=e>>11;
    int k=kc*32+((l>>4)<<3)+i, c=t*16+(l&15);
    float wv = W2[k*64+c];
    short h=f2bf(wv); bW2hi[e]=h; bW2lo[e]=f2bf(wv-bf2f(h));
  }
}

// ---------------- gemm1 (MFMA): z = feat[:,1:97] @ W1[32:,:] + embW1[op], z bf16 [node][cfg][64] ----------------
__global__ __launch_bounds__(256) void k_gemm1(const float* __restrict__ feat,
    const float* __restrict__ embW1,
    const short* __restrict__ bW1hi, const short* __restrict__ bW1lo,
    unsigned short* __restrict__ z_all){
  __shared__ float lds_f[64*FEAT];      // 24832 B, flat [row][97]
  int tid = threadIdx.x;
  int nb = blockIdx.x * 64;
  int cfg = blockIdx.y;
  const float* f = feat + (size_t)cfg*NN*FEAT;
  const float* gsrc = f + (size_t)nb*FEAT;
  int nvalid = (min(64, NN-nb))*FEAT;

  for(int idx = tid; idx < 1552; idx += 256){
    int base = idx*4;
    float4 v;
    if(base + 3 < nvalid) v = *(const float4*)(gsrc + base);
    else {
      v.x = (base+0 < nvalid) ? gsrc[base+0] : 0.f;
      v.y = (base+1 < nvalid) ? gsrc[base+1] : 0.f;
      v.z = (base+2 < nvalid) ? gsrc[base+2] : 0.f;
      v.w = (base+3 < nvalid) ? gsrc[base+3] : 0.f;
    }
    *(float4*)&lds_f[base] = v;
  }
  __syncthreads();

  int w = tid >> 6, l = tid & 63;
  int lrow = w*16 + (l & 15);
  int g8 = (l >> 4) << 3;

  f32x4 acc[4] = {{0,0,0,0},{0,0,0,0},{0,0,0,0},{0,0,0,0}};
  #pragma unroll
  for(int kc = 0; kc < 3; kc++){
    const float* ap = &lds_f[lrow*FEAT + 1 + g8 + kc*32];
    bf16x8 ahi, alo;
    #pragma unroll
    for(int i=0;i<8;i++){
      float a = ap[i];
      short h = f2bf(a);
      ahi[i] = h;
      alo[i] = f2bf(a - bf2f(h));
    }
    #pragma unroll
    for(int t=0;t<4;t++){
      const bf16x8 bh = *(const bf16x8*)&bW1hi[((kc*4 + t)*64 + l)*8];
      const bf16x8 bl = *(const bf16x8*)&bW1lo[((kc*4 + t)*64 + l)*8];
      acc[t] = __builtin_amdgcn_mfma_f32_16x16x32_bf16(ahi, bh, acc[t], 0,0,0);
      acc[t] = __builtin_amdgcn_mfma_f32_16x16x32_bf16(alo, bh, acc[t], 0,0,0);
      acc[t] = __builtin_amdgcn_mfma_f32_16x16x32_bf16(ahi, bl, acc[t], 0,0,0);
    }
  }
  int r0 = w*16 + ((l>>4)<<2);
  int cb = l & 15;
  #pragma unroll
  for(int j=0;j<4;j++){
    int node = nb + r0 + j;
    if(node < NN){
      int op = (int)lds_f[(r0+j)*FEAT];
      #pragma unroll
      for(int t=0;t<4;t++){
        int c = t*16 + cb;
        z_all[((size_t)node*NCFG + cfg)*64 + c] = (unsigned short)f2bf(acc[t][j] + embW1[op*64 + c]);
      }
    }
  }
}

// ---------------- gather1: h[n][c] = relu(inv*sum_nb z[nb][c] + b1) ----------------
__global__ __launch_bounds__(256) void k_gather1(const int* __restrict__ rowptr,
    const int* __restrict__ col, const float* __restrict__ inv_deg,
    const unsigned short* __restrict__ z_all, const float* __restrict__ b1,
    unsigned short* __restrict__ h_all){
  int tid = threadIdx.x, lane = tid & 63;
  int n = (blockIdx.x << 2) + (tid >> 6);
  if(n >= NN) return;
  int sub = lane & 7;
  const unsigned short* zl = z_all + lane*8;
  int kb = __builtin_amdgcn_readfirstlane(rowptr[n]);
  int ke = __builtin_amdgcn_readfirstlane(rowptr[n+1]);
  float acc[8] = {0,0,0,0,0,0,0,0};
  for(int k = kb; k < ke; k++){
    int d = __builtin_amdgcn_readfirstlane(col[k]);
    const bf16x8 v = *(const bf16x8*)(zl + (size_t)d*512);
    #pragma unroll
    for(int i=0;i<8;i++) acc[i] += bf2f(v[i]);
  }
  float inv = inv_deg[n];
  const float4 bA = *(const float4*)(b1 + sub*8);
  const float4 bB = *(const float4*)(b1 + sub*8 + 4);
  float bv[8] = {bA.x,bA.y,bA.z,bA.w,bB.x,bB.y,bB.z,bB.w};
  bf16x8 o;
  #pragma unroll
  for(int i=0;i<8;i++) o[i] = f2bf(fmaxf(fmaf(acc[i], inv, bv[i]), 0.f));
  *(bf16x8*)(h_all + (size_t)n*512 + lane*8) = o;
}

// ---------------- gather2W: r = |relu((mean_agg h) @ W2 + b2) . Wp + bp| ----------------
// block = 16 nodes; phase1 gather-agg into LDS V [128 rows=(node,cfg)][68], phase2 MFMA @ W2 + epilogue
__global__ __launch_bounds__(256) void k_gather2W(const int* __restrict__ rowptr,
    const int* __restrict__ col, const float* __restrict__ inv_deg,
    const unsigned short* __restrict__ h_all,
    const short* __restrict__ bW2hi, const short* __restrict__ bW2lo,
    const float* __restrict__ b2, const float* __restrict__ Wp,
    const float* __restrict__ bp, float* __restrict__ r_all){
  __shared__ unsigned short V[128][68];   // 17.4 KB, row = node_local*8 + cfg, pad 68 (bank step 2)
  int tid = threadIdx.x, lane = tid & 63, w = tid >> 6;
  int nb = blockIdx.x * 16;
  int cfg = lane >> 3, sub = lane & 7;
  const unsigned short* hl = h_all + lane*8;

  // phase 1: each wave aggregates 4 nodes (mean, no bias/relu — reference order)
  for(int i = 0; i < 4; i++){
    int nl = w*4 + i;
    int n = nb + nl;
    int kb = __builtin_amdgcn_readfirstlane(rowptr[n]);
    int ke = __builtin_amdgcn_readfirstlane(rowptr[n+1]);
    float acc[8] = {0,0,0,0,0,0,0,0};
    for(int k = kb; k < ke; k++){
      int d = __builtin_amdgcn_readfirstlane(col[k]);
      const bf16x8 v = *(const bf16x8*)(hl + (size_t)d*512);
      #pragma unroll
      for(int j=0;j<8;j++) acc[j] += bf2f(v[j]);
    }
    float inv = inv_deg[n];
    bf16x8 o;
    #pragma unroll
    for(int j=0;j<8;j++) o[j] = f2bf(acc[j] * inv);
    *(bf16x8*)&V[nl*8 + cfg][sub*8] = o;
  }
  __syncthreads();

  // phase 2: 2 A-tiles per wave; u = V @ W2 (hi+lo), then relu(u+b2).Wp reduce
  float bp0 = bp[0];
  int cb = lane & 15;
  int koff = (lane >> 4) << 3;
  #pragma unroll
  for(int at = 0; at < 2; at++){
    int tile = w*2 + at;                 // 0..7
    int trow = tile*16 + cb;
    f32x4 acc[4] = {{0,0,0,0},{0,0,0,0},{0,0,0,0},{0,0,0,0}};
    #pragma unroll
    for(int kc = 0; kc < 2; kc++){
      const bf16x8 a = *(const bf16x8*)&V[trow][kc*32 + koff];
      #pragma unroll
      for(int t=0;t<4;t++){
        const bf16x8 bh = *(const bf16x8*)&bW2hi[((kc*4+t)*64 + lane)*8];
        const bf16x8 bl = *(const bf16x8*)&bW2lo[((kc*4+t)*64 + lane)*8];
        acc[t] = __builtin_amdgcn_mfma_f32_16x16x32_bf16(a, bh, acc[t], 0,0,0);
        acc[t] = __builtin_amdgcn_mfma_f32_16x16x32_bf16(a, bl, acc[t], 0,0,0);
      }
    }
    float part[4];
    #pragma unroll
    for(int j=0;j<4;j++){
      float p = 0.f;
      #pragma unroll
      for(int t=0;t<4;t++){
        int c = t*16 + cb;
        p += fmaxf(acc[t][j] + b2[c], 0.f) * Wp[c];
      }
      part[j] = p;
    }
    #pragma unroll
    for(int off=1; off<16; off<<=1){
      #pragma unroll
      for(int j=0;j<4;j++) part[j] += __shfl_xor(part[j], off, 64);
    }
    if(cb == 0){
      #pragma unroll
      for(int j=0;j<4;j++){
        int row = tile*16 + ((lane>>4)<<2) + j;   // 0..127 within block
        int node = nb + (row >> 3);
        int cfgo = row & 7;
        r_all[(size_t)cfgo*NN + node] = fabsf(part[j] + bp0);
      }
    }
  }
}

// ---------------- pool ----------------
__global__ __launch_bounds__(256) void k_pool(const float* __restrict__ r_all,
    const int* __restrict__ off, float* __restrict__ out){
  __shared__ float red[256];
  int b = blockIdx.x;               // b = g*8 + c
  int g = b >> 3, c = b & 7;
  int lo = off[g], hi = off[g+1];
  float s = 0.f;
  for(int i = lo + (int)threadIdx.x; i < hi; i += 256) s += r_all[(size_t)c*NN + i];
  red[threadIdx.x] = s;
  __syncthreads();
  for(int w=128; w>0; w>>=1){
    if((int)threadIdx.x < w) red[threadIdx.x] += red[threadIdx.x + w];
    __syncthreads();
  }
  if(threadIdx.x == 0) out[b] = red[0];
}

extern "C" void kernel_launch(void* const* d_in, const int* in_sizes, int n_in,
                              void* d_out, int out_size, void* d_ws, size_t ws_size,
                              hipStream_t stream){
  (void)in_sizes; (void)n_in; (void)out_size; (void)ws_size;
  const float* feat = (const float*)d_in[0];
  const int*   eidx = (const int*)d_in[1];
  const int*   lens = (const int*)d_in[2];
  const float* emb  = (const float*)d_in[3];
  const float* W1   = (const float*)d_in[4];
  const float* b1   = (const float*)d_in[5];
  const float* W2   = (const float*)d_in[6];
  const float* b2   = (const float*)d_in[7];
  const float* Wp   = (const float*)d_in[8];
  const float* bp   = (const float*)d_in[9];
  float* out = (float*)d_out;
  const int* src = eidx;
  const int* dst = eidx + NE;

  char* ws = (char*)d_ws;
  size_t o = 0;
  auto alloc = [&](size_t bytes)->char*{ char* p = ws + o; o = (o + bytes + 255) & ~(size_t)255; return p; };
  int*   rowptr  = (int*)  alloc((NN+1)*4);
  int*   cursor  = (int*)  alloc((size_t)NN*4);
  int*   colx    = (int*)  alloc((size_t)NE*4);
  float* invd    = (float*)alloc((size_t)NN*4);
  int*   goff    = (int*)  alloc((NG+1)*4);
  int*   spart   = (int*)  alloc(SCAN_BLOCKS*4);
  float* eW1     = (float*)alloc(128*64*4);
  short* bW1hi   = (short*)alloc(3*4*64*8*2);
  short* bW1lo   = (short*)alloc(3*4*64*8*2);
  short* bW2hi   = (short*)alloc(2*4*64*8*2);
  short* bW2lo   = (short*)alloc(2*4*64*8*2);
  float* r_all   = (float*)alloc((size_t)NCFG*NN*4);
  unsigned short* z_all = (unsigned short*)alloc((size_t)NN*NCFG*64*2);  // 102.4 MB, [node][cfg][64]
  unsigned short* h_all = (unsigned short*)alloc((size_t)NN*NCFG*64*2);  // 102.4 MB

  hipMemsetAsync(cursor, 0, (size_t)NN*4, stream);
  k_hist   <<<(NE+255)/256, 256, 0, stream>>>(src, cursor, NE);
  k_scanA  <<<SCAN_BLOCKS, 1024, 0, stream>>>(cursor, spart, NN);
  k_scanB  <<<1, 64, 0, stream>>>(spart, rowptr, SCAN_BLOCKS, NN);
  k_scanC  <<<SCAN_BLOCKS, 1024, 0, stream>>>(cursor, spart, rowptr, invd, NN);
  k_fill   <<<(NE+255)/256, 256, 0, stream>>>(src, dst, cursor, colx, NE);
  k_embW1  <<<128, 64, 0, stream>>>(emb, W1, eW1);
  k_prepB  <<<24, 256, 0, stream>>>(W1, W2, bW1hi, bW1lo, bW2hi, bW2lo);
  k_offsets<<<1, 64, 0, stream>>>(lens, goff);

  dim3 ggemm((NN+63)/64, NCFG);
  k_gemm1  <<<ggemm, 256, 0, stream>>>(feat, eW1, bW1hi, bW1lo, z_all);
  k_gather1<<<(NN+3)/4, 256, 0, stream>>>(rowptr, colx, invd, z_all, b1, h_all);
  k_gather2W<<<NN/16, 256, 0, stream>>>(rowptr, colx, invd, h_all, bW2hi, bW2lo, b2, Wp, bp, r_all);
  k_pool   <<<NCFG*NG, 256, 0, stream>>>(r_all, goff, out);
}

// Round 7
// 366.972 us; speedup vs baseline: 4.7275x; 1.0024x over previous
//
#include <hip/hip_runtime.h>

#define NCFG 8
#define NN 100000
#define NE 400000
#define NG 10
#define FEAT 97
#define SCAN_BLOCKS 25   // ceil(NN/4096)

typedef __attribute__((ext_vector_type(8))) short bf16x8;
typedef __attribute__((ext_vector_type(4))) float f32x4;

__device__ inline short f2bf(float x){
  unsigned u = __float_as_uint(x);
  unsigned r = u + 0x7FFFu + ((u >> 16) & 1u);
  return (short)(r >> 16);
}
__device__ inline float bf2f(short h){
  return __uint_as_float(((unsigned)(unsigned short)h) << 16);
}

// ---------------- CSR build ----------------
__global__ void k_hist(const int* __restrict__ src, int* __restrict__ deg, int e_count){
  int e = blockIdx.x*blockDim.x + threadIdx.x;
  if(e < e_count) atomicAdd(&deg[src[e]], 1);
}

__global__ __launch_bounds__(1024) void k_scanA(const int* __restrict__ deg,
    int* __restrict__ partial, int n){
  __shared__ int ws[16];
  int tid = threadIdx.x;
  int i0 = blockIdx.x*4096 + tid*4;
  int s = 0;
  #pragma unroll
  for(int i=0;i<4;i++) if(i0+i < n) s += deg[i0+i];
  #pragma unroll
  for(int off=1; off<64; off<<=1) s += __shfl_xor(s, off, 64);
  if((tid & 63) == 0) ws[tid >> 6] = s;
  __syncthreads();
  if(tid < 16){
    int v = ws[tid];
    #pragma unroll
    for(int off=1; off<16; off<<=1) v += __shfl_xor(v, off, 16);
    if(tid == 0) partial[blockIdx.x] = v;
  }
}

__global__ void k_scanB(int* __restrict__ partial, int* __restrict__ rowptr, int nb, int n){
  int tid = threadIdx.x;   // 64
  int v = (tid < nb) ? partial[tid] : 0;
  int x = v;
  #pragma unroll
  for(int off=1; off<64; off<<=1){
    int t = __shfl_up(x, off, 64);
    if(tid >= off) x += t;
  }
  if(tid < nb) partial[tid] = x - v;
  if(tid == nb-1) rowptr[n] = x;
}

__global__ __launch_bounds__(1024) void k_scanC(int* __restrict__ deg_cur,
    const int* __restrict__ partial, int* __restrict__ rowptr,
    float* __restrict__ inv_deg, int n){
  __shared__ int wsum[16];
  int tid = threadIdx.x, lane = tid & 63, w = tid >> 6;
  int i0 = blockIdx.x*4096 + tid*4;
  int v0 = (i0+0 < n) ? deg_cur[i0+0] : 0;
  int v1 = (i0+1 < n) ? deg_cur[i0+1] : 0;
  int v2 = (i0+2 < n) ? deg_cur[i0+2] : 0;
  int v3 = (i0+3 < n) ? deg_cur[i0+3] : 0;
  int s = v0+v1+v2+v3;
  int x = s;
  #pragma unroll
  for(int off=1; off<64; off<<=1){
    int t = __shfl_up(x, off, 64);
    if(lane >= off) x += t;
  }
  if(lane == 63) wsum[w] = x;
  __syncthreads();
  if(w == 0){
    int y = (lane < 16) ? wsum[lane] : 0;
    #pragma unroll
    for(int off=1; off<16; off<<=1){
      int t = __shfl_up(y, off, 64);
      if(lane >= off) y += t;
    }
    if(lane < 16) wsum[lane] = y;
  }
  __syncthreads();
  int waveoff = (w > 0) ? wsum[w-1] : 0;
  int run = partial[blockIdx.x] + waveoff + (x - s);
  if(i0+0 < n){ rowptr[i0+0]=run; deg_cur[i0+0]=run; inv_deg[i0+0]=1.0f/(float)max(v0,1); run+=v0; }
  if(i0+1 < n){ rowptr[i0+1]=run; deg_cur[i0+1]=run; inv_deg[i0+1]=1.0f/(float)max(v1,1); run+=v1; }
  if(i0+2 < n){ rowptr[i0+2]=run; deg_cur[i0+2]=run; inv_deg[i0+2]=1.0f/(float)max(v2,1); run+=v2; }
  if(i0+3 < n){ rowptr[i0+3]=run; deg_cur[i0+3]=run; inv_deg[i0+3]=1.0f/(float)max(v3,1); run+=v3; }
}

__global__ void k_fill(const int* __restrict__ src, const int* __restrict__ dst,
                       int* __restrict__ cursor, int* __restrict__ col, int e_count){
  int e = blockIdx.x*blockDim.x + threadIdx.x;
  if(e < e_count){
    int pos = atomicAdd(&cursor[src[e]], 1);
    col[pos] = dst[e];
  }
}

__global__ void k_embW1(const float* __restrict__ emb, const float* __restrict__ W1,
                        float* __restrict__ embW1){
  int o = blockIdx.x, j = threadIdx.x;
  float s = 0.f;
  #pragma unroll
  for(int k=0;k<32;k++) s += emb[o*32+k] * W1[k*64+j];
  embW1[o*64+j] = s;
}

__global__ void k_offsets(const int* __restrict__ lengths, int* __restrict__ off){
  if(threadIdx.x == 0){
    int s = 0;
    for(int g=0; g<NG; g++){ off[g] = s; s += lengths[g]; }
    off[NG] = s;
  }
}

// ---------------- prep B fragments (once): frag-order [kc][t][lane][8], bf16 hi/lo ----------------
__global__ __launch_bounds__(256) void k_prepB(const float* __restrict__ W1, const float* __restrict__ W2,
    short* __restrict__ bW1hi, short* __restrict__ bW1lo,
    short* __restrict__ bW2hi, short* __restrict__ bW2lo){
  int e = blockIdx.x*256 + threadIdx.x;
  if(e < 3*4*64*8){
    int i=e&7, l=(e>>3)&63, t=(e>>9)&3, kc=e>>11;
    int k=kc*32+((l>>4)<<3)+i, c=t*16+(l&15);
    float wv = W1[(32+k)*64+c];
    short h=f2bf(wv); bW1hi[e]=h; bW1lo[e]=f2bf(wv-bf2f(h));
  }
  if(e < 2*4*64*8){
    int i=e&7, l=(e>>3)&63, t=(e>>9)&3, kc=e>>11;
    int k=kc*32+((l>>4)<<3)+i, c=t*16+(l&15);
    float wv = W2[k*64+c];
    short h=f2bf(wv); bW2hi[e]=h; bW2lo[e]=f2bf(wv-bf2f(h));
  }
}

// ---------------- gemm1 (MFMA, swapped operands): z^T tiles = W1^T @ feat^T ----------------
// D: row = feature (g*4+j within tile t), col = node (lane&15) -> lane owns 4 consecutive
// features per tile -> packed 8B stores. A = bW1 frags, B = feat frag (same lane layout).
__global__ __launch_bounds__(256) void k_gemm1(const float* __restrict__ feat,
    const float* __restrict__ embW1,
    const short* __restrict__ bW1hi, const short* __restrict__ bW1lo,
    unsigned short* __restrict__ z_all){
  __shared__ float lds_f[64*FEAT];      // 24832 B, flat [row][97]
  int tid = threadIdx.x;
  int nb = blockIdx.x * 64;
  int cfg = blockIdx.y;
  const float* gsrc = feat + ((size_t)cfg*NN + nb)*FEAT;

  if(nb + 64 <= NN){
    for(int idx = tid; idx < 1552; idx += 256)
      *(float4*)&lds_f[idx*4] = *(const float4*)(gsrc + idx*4);
  } else {
    int nvalid = (NN - nb)*FEAT;
    for(int idx = tid; idx < 1552; idx += 256){
      int base = idx*4;
      float4 v;
      v.x = (base+0 < nvalid) ? gsrc[base+0] : 0.f;
      v.y = (base+1 < nvalid) ? gsrc[base+1] : 0.f;
      v.z = (base+2 < nvalid) ? gsrc[base+2] : 0.f;
      v.w = (base+3 < nvalid) ? gsrc[base+3] : 0.f;
      *(float4*)&lds_f[base] = v;
    }
  }
  __syncthreads();

  int w = tid >> 6, l = tid & 63;
  int node_loc = w*16 + (l & 15);
  int g8 = (l >> 4) << 3;

  f32x4 acc[4] = {{0,0,0,0},{0,0,0,0},{0,0,0,0},{0,0,0,0}};
  #pragma unroll
  for(int kc = 0; kc < 3; kc++){
    const float* ap = &lds_f[node_loc*FEAT + 1 + g8 + kc*32];
    bf16x8 bfeat;
    #pragma unroll
    for(int i=0;i<8;i++) bfeat[i] = f2bf(ap[i]);
    #pragma unroll
    for(int t=0;t<4;t++){
      const bf16x8 ah = *(const bf16x8*)&bW1hi[((kc*4 + t)*64 + l)*8];
      const bf16x8 al = *(const bf16x8*)&bW1lo[((kc*4 + t)*64 + l)*8];
      acc[t] = __builtin_amdgcn_mfma_f32_16x16x32_bf16(ah, bfeat, acc[t], 0,0,0);
      acc[t] = __builtin_amdgcn_mfma_f32_16x16x32_bf16(al, bfeat, acc[t], 0,0,0);
    }
  }
  int node = nb + node_loc;
  int g = l >> 4;
  if(node < NN){
    int op = (int)lds_f[node_loc*FEAT];
    unsigned short* zrow = z_all + ((size_t)node*NCFG + cfg)*64;
    #pragma unroll
    for(int t=0;t<4;t++){
      int f0 = t*16 + g*4;
      const float4 e = *(const float4*)&embW1[op*64 + f0];
      ushort4 pk;
      pk.x = (unsigned short)f2bf(acc[t][0] + e.x);
      pk.y = (unsigned short)f2bf(acc[t][1] + e.y);
      pk.z = (unsigned short)f2bf(acc[t][2] + e.z);
      pk.w = (unsigned short)f2bf(acc[t][3] + e.w);
      *(ushort4*)(zrow + f0) = pk;
    }
  }
}

// ---------------- gather1: h[n][c] = relu(inv*sum_nb z[nb][c] + b1), 4-chain ILP ----------------
__global__ __launch_bounds__(256) void k_gather1(const int* __restrict__ rowptr,
    const int* __restrict__ col, const float* __restrict__ inv_deg,
    const unsigned short* __restrict__ z_all, const float* __restrict__ b1,
    unsigned short* __restrict__ h_all){
  int tid = threadIdx.x, lane = tid & 63;
  int n = (blockIdx.x << 2) + (tid >> 6);
  if(n >= NN) return;
  int sub = lane & 7;
  const unsigned short* zl = z_all + lane*8;
  int kb = rowptr[n], ke = rowptr[n+1];
  float a0[8]={0,0,0,0,0,0,0,0}, a1[8]={0,0,0,0,0,0,0,0};
  float a2[8]={0,0,0,0,0,0,0,0}, a3[8]={0,0,0,0,0,0,0,0};
  int k = kb;
  for(; k+4 <= ke; k += 4){
    int d0=col[k], d1=col[k+1], d2=col[k+2], d3=col[k+3];
    const bf16x8 v0 = *(const bf16x8*)(zl + (size_t)d0*512);
    const bf16x8 v1 = *(const bf16x8*)(zl + (size_t)d1*512);
    const bf16x8 v2 = *(const bf16x8*)(zl + (size_t)d2*512);
    const bf16x8 v3 = *(const bf16x8*)(zl + (size_t)d3*512);
    #pragma unroll
    for(int i=0;i<8;i++){
      a0[i] += bf2f(v0[i]); a1[i] += bf2f(v1[i]);
      a2[i] += bf2f(v2[i]); a3[i] += bf2f(v3[i]);
    }
  }
  for(; k < ke; k++){
    int d = col[k];
    const bf16x8 v = *(const bf16x8*)(zl + (size_t)d*512);
    #pragma unroll
    for(int i=0;i<8;i++) a0[i] += bf2f(v[i]);
  }
  float inv = inv_deg[n];
  const float4 bA = *(const float4*)(b1 + sub*8);
  const float4 bB = *(const float4*)(b1 + sub*8 + 4);
  float bv[8] = {bA.x,bA.y,bA.z,bA.w,bB.x,bB.y,bB.z,bB.w};
  bf16x8 o;
  #pragma unroll
  for(int i=0;i<8;i++){
    float acc = (a0[i]+a1[i]) + (a2[i]+a3[i]);
    o[i] = f2bf(fmaxf(fmaf(acc, inv, bv[i]), 0.f));
  }
  *(bf16x8*)(h_all + (size_t)n*512 + lane*8) = o;
}

// ---------------- gather2W: r = |relu((mean_agg h) @ W2 + b2) . Wp + bp| ----------------
__global__ __launch_bounds__(256) void k_gather2W(const int* __restrict__ rowptr,
    const int* __restrict__ col, const float* __restrict__ inv_deg,
    const unsigned short* __restrict__ h_all,
    const short* __restrict__ bW2hi, const short* __restrict__ bW2lo,
    const float* __restrict__ b2, const float* __restrict__ Wp,
    const float* __restrict__ bp, float* __restrict__ r_all){
  __shared__ unsigned short V[128][68];   // row = node_local*8 + cfg
  int tid = threadIdx.x, lane = tid & 63, w = tid >> 6;
  int nb = blockIdx.x * 16;
  int cfg = lane >> 3, sub = lane & 7;
  const unsigned short* hl = h_all + lane*8;

  // phase 1: each wave aggregates 4 nodes, 4-chain ILP
  for(int i = 0; i < 4; i++){
    int nl = w*4 + i;
    int n = nb + nl;
    int kb = rowptr[n], ke = rowptr[n+1];
    float a0[8]={0,0,0,0,0,0,0,0}, a1[8]={0,0,0,0,0,0,0,0};
    float a2[8]={0,0,0,0,0,0,0,0}, a3[8]={0,0,0,0,0,0,0,0};
    int k = kb;
    for(; k+4 <= ke; k += 4){
      int d0=col[k], d1=col[k+1], d2=col[k+2], d3=col[k+3];
      const bf16x8 v0 = *(const bf16x8*)(hl + (size_t)d0*512);
      const bf16x8 v1 = *(const bf16x8*)(hl + (size_t)d1*512);
      const bf16x8 v2 = *(const bf16x8*)(hl + (size_t)d2*512);
      const bf16x8 v3 = *(const bf16x8*)(hl + (size_t)d3*512);
      #pragma unroll
      for(int j=0;j<8;j++){
        a0[j] += bf2f(v0[j]); a1[j] += bf2f(v1[j]);
        a2[j] += bf2f(v2[j]); a3[j] += bf2f(v3[j]);
      }
    }
    for(; k < ke; k++){
      int d = col[k];
      const bf16x8 v = *(const bf16x8*)(hl + (size_t)d*512);
      #pragma unroll
      for(int j=0;j<8;j++) a0[j] += bf2f(v[j]);
    }
    float inv = inv_deg[n];
    bf16x8 o;
    #pragma unroll
    for(int j=0;j<8;j++){
      float acc = (a0[j]+a1[j]) + (a2[j]+a3[j]);
      o[j] = f2bf(acc * inv);
    }
    *(bf16x8*)&V[nl*8 + cfg][sub*8] = o;
  }
  __syncthreads();

  // phase 2: 2 A-tiles per wave; u = V @ W2 (hi+lo), then relu(u+b2).Wp reduce
  float bp0 = bp[0];
  int cb = lane & 15;
  int koff = (lane >> 4) << 3;
  #pragma unroll
  for(int at = 0; at < 2; at++){
    int tile = w*2 + at;                 // 0..7
    int trow = tile*16 + cb;
    f32x4 acc[4] = {{0,0,0,0},{0,0,0,0},{0,0,0,0},{0,0,0,0}};
    #pragma unroll
    for(int kc = 0; kc < 2; kc++){
      const bf16x8 a = *(const bf16x8*)&V[trow][kc*32 + koff];
      #pragma unroll
      for(int t=0;t<4;t++){
        const bf16x8 bh = *(const bf16x8*)&bW2hi[((kc*4+t)*64 + lane)*8];
        const bf16x8 bl = *(const bf16x8*)&bW2lo[((kc*4+t)*64 + lane)*8];
        acc[t] = __builtin_amdgcn_mfma_f32_16x16x32_bf16(a, bh, acc[t], 0,0,0);
        acc[t] = __builtin_amdgcn_mfma_f32_16x16x32_bf16(a, bl, acc[t], 0,0,0);
      }
    }
    float part[4];
    #pragma unroll
    for(int j=0;j<4;j++){
      float p = 0.f;
      #pragma unroll
      for(int t=0;t<4;t++){
        int c = t*16 + cb;
        p += fmaxf(acc[t][j] + b2[c], 0.f) * Wp[c];
      }
      part[j] = p;
    }
    #pragma unroll
    for(int off=1; off<16; off<<=1){
      #pragma unroll
      for(int j=0;j<4;j++) part[j] += __shfl_xor(part[j], off, 64);
    }
    if(cb == 0){
      #pragma unroll
      for(int j=0;j<4;j++){
        int row = tile*16 + ((lane>>4)<<2) + j;   // 0..127 within block
        int node = nb + (row >> 3);
        int cfgo = row & 7;
        r_all[(size_t)cfgo*NN + node] = fabsf(part[j] + bp0);
      }
    }
  }
}

// ---------------- pool ----------------
__global__ __launch_bounds__(256) void k_pool(const float* __restrict__ r_all,
    const int* __restrict__ off, float* __restrict__ out){
  __shared__ float red[256];
  int b = blockIdx.x;               // b = g*8 + c
  int g = b >> 3, c = b & 7;
  int lo = off[g], hi = off[g+1];
  float s = 0.f;
  for(int i = lo + (int)threadIdx.x; i < hi; i += 256) s += r_all[(size_t)c*NN + i];
  red[threadIdx.x] = s;
  __syncthreads();
  for(int w=128; w>0; w>>=1){
    if((int)threadIdx.x < w) red[threadIdx.x] += red[threadIdx.x + w];
    __syncthreads();
  }
  if(threadIdx.x == 0) out[b] = red[0];
}

extern "C" void kernel_launch(void* const* d_in, const int* in_sizes, int n_in,
                              void* d_out, int out_size, void* d_ws, size_t ws_size,
                              hipStream_t stream){
  (void)in_sizes; (void)n_in; (void)out_size; (void)ws_size;
  const float* feat = (const float*)d_in[0];
  const int*   eidx = (const int*)d_in[1];
  const int*   lens = (const int*)d_in[2];
  const float* emb  = (const float*)d_in[3];
  const float* W1   = (const float*)d_in[4];
  const float* b1   = (const float*)d_in[5];
  const float* W2   = (const float*)d_in[6];
  const float* b2   = (const float*)d_in[7];
  const float* Wp   = (const float*)d_in[8];
  const float* bp   = (const float*)d_in[9];
  float* out = (float*)d_out;
  const int* src = eidx;
  const int* dst = eidx + NE;

  char* ws = (char*)d_ws;
  size_t o = 0;
  auto alloc = [&](size_t bytes)->char*{ char* p = ws + o; o = (o + bytes + 255) & ~(size_t)255; return p; };
  int*   rowptr  = (int*)  alloc((NN+1)*4);
  int*   cursor  = (int*)  alloc((size_t)NN*4);
  int*   colx    = (int*)  alloc((size_t)NE*4);
  float* invd    = (float*)alloc((size_t)NN*4);
  int*   goff    = (int*)  alloc((NG+1)*4);
  int*   spart   = (int*)  alloc(SCAN_BLOCKS*4);
  float* eW1     = (float*)alloc(128*64*4);
  short* bW1hi   = (short*)alloc(3*4*64*8*2);
  short* bW1lo   = (short*)alloc(3*4*64*8*2);
  short* bW2hi   = (short*)alloc(2*4*64*8*2);
  short* bW2lo   = (short*)alloc(2*4*64*8*2);
  float* r_all   = (float*)alloc((size_t)NCFG*NN*4);
  unsigned short* z_all = (unsigned short*)alloc((size_t)NN*NCFG*64*2);  // 102.4 MB, [node][cfg][64]
  unsigned short* h_all = (unsigned short*)alloc((size_t)NN*NCFG*64*2);  // 102.4 MB

  hipMemsetAsync(cursor, 0, (size_t)NN*4, stream);
  k_hist   <<<(NE+255)/256, 256, 0, stream>>>(src, cursor, NE);
  k_scanA  <<<SCAN_BLOCKS, 1024, 0, stream>>>(cursor, spart, NN);
  k_scanB  <<<1, 64, 0, stream>>>(spart, rowptr, SCAN_BLOCKS, NN);
  k_scanC  <<<SCAN_BLOCKS, 1024, 0, stream>>>(cursor, spart, rowptr, invd, NN);
  k_fill   <<<(NE+255)/256, 256, 0, stream>>>(src, dst, cursor, colx, NE);
  k_embW1  <<<128, 64, 0, stream>>>(emb, W1, eW1);
  k_prepB  <<<24, 256, 0, stream>>>(W1, W2, bW1hi, bW1lo, bW2hi, bW2lo);
  k_offsets<<<1, 64, 0, stream>>>(lens, goff);

  dim3 ggemm((NN+63)/64, NCFG);
  k_gemm1  <<<ggemm, 256, 0, stream>>>(feat, eW1, bW1hi, bW1lo, z_all);
  k_gather1<<<(NN+3)/4, 256, 0, stream>>>(rowptr, colx, invd, z_all, b1, h_all);
  k_gather2W<<<NN/16, 256, 0, stream>>>(rowptr, colx, invd, h_all, bW2hi, bW2lo, b2, Wp, bp, r_all);
  k_pool   <<<NCFG*NG, 256, 0, stream>>>(r_all, goff, out);
}